// Round 2
// baseline (390.589 us; speedup 1.0000x reference)
//
#include <hip/hip_runtime.h>

#define SEQ 4096
#define DM  768
#define NH  12
#define DK  64

typedef __bf16 bf16_t;
typedef bf16_t bf16x8 __attribute__((ext_vector_type(8)));
typedef bf16_t bf16x4 __attribute__((ext_vector_type(4)));
typedef float  f32x4  __attribute__((ext_vector_type(4)));

#define LOG2E 1.44269504088896340736f

// ---------------------------------------------------------------------------
// GEMM: C[M,N] = A[M,K] * W[N,K]^T + bias, A fp32, W fp32, C bf16.
// Fused over z = {Q,K,V}. Tile 128x128, BK=32, 4 waves each 64x64.
// ---------------------------------------------------------------------------
__global__ __launch_bounds__(256) void gemm_qkv(
    const float* __restrict__ x,
    const float* __restrict__ Wq, const float* __restrict__ bq,
    const float* __restrict__ Wk, const float* __restrict__ bk,
    const float* __restrict__ Wv, const float* __restrict__ bv,
    bf16_t* __restrict__ Qb, bf16_t* __restrict__ Kb, bf16_t* __restrict__ Vb)
{
    const float* W; const float* bias; bf16_t* Cout;
    if (blockIdx.z == 0)      { W = Wq; bias = bq; Cout = Qb; }
    else if (blockIdx.z == 1) { W = Wk; bias = bk; Cout = Kb; }
    else                      { W = Wv; bias = bv; Cout = Vb; }

    __shared__ bf16_t As[128][40];   // BK=32 + 8 pad -> stride 80B, 2-way (free)
    __shared__ bf16_t Bs[128][40];

    const int tid  = threadIdx.x;
    const int wave = tid >> 6;
    const int lane = tid & 63;
    const int wm   = wave & 1, wn = wave >> 1;
    const int lrow = lane & 15;
    const int quad = lane >> 4;
    const int row0 = blockIdx.x * 128;
    const int col0 = blockIdx.y * 128;

    f32x4 acc[4][4];
    #pragma unroll
    for (int i = 0; i < 4; i++)
        #pragma unroll
        for (int j = 0; j < 4; j++)
            acc[i][j] = (f32x4){0.f, 0.f, 0.f, 0.f};

    for (int k0 = 0; k0 < DM; k0 += 32) {
        __syncthreads();
        // stage A (x) and B (W) tiles, fp32 -> bf16 during staging
        #pragma unroll
        for (int i = 0; i < 4; i++) {
            int v  = tid + i * 256;      // 1024 float4 vectors per matrix
            int r  = v >> 3;             // 8 float4 per 32-col row
            int c4 = v & 7;
            float4 av = *(const float4*)&x[(size_t)(row0 + r) * DM + k0 + c4 * 4];
            bf16x4 at;
            at[0] = (bf16_t)av.x; at[1] = (bf16_t)av.y;
            at[2] = (bf16_t)av.z; at[3] = (bf16_t)av.w;
            *(bf16x4*)&As[r][c4 * 4] = at;
            float4 bv4 = *(const float4*)&W[(size_t)(col0 + r) * DM + k0 + c4 * 4];
            bf16x4 bt;
            bt[0] = (bf16_t)bv4.x; bt[1] = (bf16_t)bv4.y;
            bt[2] = (bf16_t)bv4.z; bt[3] = (bf16_t)bv4.w;
            *(bf16x4*)&Bs[r][c4 * 4] = bt;
        }
        __syncthreads();

        bf16x8 afrag[4], bfrag[4];
        #pragma unroll
        for (int mt = 0; mt < 4; mt++)
            afrag[mt] = *(const bf16x8*)&As[wm * 64 + mt * 16 + lrow][quad * 8];
        #pragma unroll
        for (int nt = 0; nt < 4; nt++)
            bfrag[nt] = *(const bf16x8*)&Bs[wn * 64 + nt * 16 + lrow][quad * 8];
        #pragma unroll
        for (int mt = 0; mt < 4; mt++)
            #pragma unroll
            for (int nt = 0; nt < 4; nt++)
                acc[mt][nt] = __builtin_amdgcn_mfma_f32_16x16x32_bf16(
                    afrag[mt], bfrag[nt], acc[mt][nt], 0, 0, 0);
    }

    // epilogue: + bias, store bf16
    #pragma unroll
    for (int nt = 0; nt < 4; nt++) {
        int col = col0 + wn * 64 + nt * 16 + lrow;
        float bv = bias[col];
        #pragma unroll
        for (int mt = 0; mt < 4; mt++) {
            #pragma unroll
            for (int r = 0; r < 4; r++) {
                int row = row0 + wm * 64 + mt * 16 + quad * 4 + r;
                Cout[(size_t)row * DM + col] = (bf16_t)(acc[mt][nt][r] + bv);
            }
        }
    }
}

// ---------------------------------------------------------------------------
// GEMM: out[M,N] = A[M,K](bf16) * W[N,K]^T(fp32) + bias, out fp32.
// ---------------------------------------------------------------------------
__global__ __launch_bounds__(256) void gemm_out(
    const bf16_t* __restrict__ A, const float* __restrict__ W,
    const float* __restrict__ bias, float* __restrict__ C)
{
    __shared__ bf16_t As[128][40];
    __shared__ bf16_t Bs[128][40];

    const int tid  = threadIdx.x;
    const int wave = tid >> 6;
    const int lane = tid & 63;
    const int wm   = wave & 1, wn = wave >> 1;
    const int lrow = lane & 15;
    const int quad = lane >> 4;
    const int row0 = blockIdx.x * 128;
    const int col0 = blockIdx.y * 128;

    f32x4 acc[4][4];
    #pragma unroll
    for (int i = 0; i < 4; i++)
        #pragma unroll
        for (int j = 0; j < 4; j++)
            acc[i][j] = (f32x4){0.f, 0.f, 0.f, 0.f};

    for (int k0 = 0; k0 < DM; k0 += 32) {
        __syncthreads();
        #pragma unroll
        for (int i = 0; i < 2; i++) {       // A: 512 bf16x8 vectors
            int v  = tid + i * 256;
            int r  = v >> 2;                // 4 vectors per 32-col row
            int c8 = v & 3;
            *(bf16x8*)&As[r][c8 * 8] =
                *(const bf16x8*)&A[(size_t)(row0 + r) * DM + k0 + c8 * 8];
        }
        #pragma unroll
        for (int i = 0; i < 4; i++) {       // B: fp32 -> bf16
            int v  = tid + i * 256;
            int r  = v >> 3;
            int c4 = v & 7;
            float4 bv4 = *(const float4*)&W[(size_t)(col0 + r) * DM + k0 + c4 * 4];
            bf16x4 bt;
            bt[0] = (bf16_t)bv4.x; bt[1] = (bf16_t)bv4.y;
            bt[2] = (bf16_t)bv4.z; bt[3] = (bf16_t)bv4.w;
            *(bf16x4*)&Bs[r][c4 * 4] = bt;
        }
        __syncthreads();

        bf16x8 afrag[4], bfrag[4];
        #pragma unroll
        for (int mt = 0; mt < 4; mt++)
            afrag[mt] = *(const bf16x8*)&As[wm * 64 + mt * 16 + lrow][quad * 8];
        #pragma unroll
        for (int nt = 0; nt < 4; nt++)
            bfrag[nt] = *(const bf16x8*)&Bs[wn * 64 + nt * 16 + lrow][quad * 8];
        #pragma unroll
        for (int mt = 0; mt < 4; mt++)
            #pragma unroll
            for (int nt = 0; nt < 4; nt++)
                acc[mt][nt] = __builtin_amdgcn_mfma_f32_16x16x32_bf16(
                    afrag[mt], bfrag[nt], acc[mt][nt], 0, 0, 0);
    }

    #pragma unroll
    for (int nt = 0; nt < 4; nt++) {
        int col = col0 + wn * 64 + nt * 16 + lrow;
        float bv = bias[col];
        #pragma unroll
        for (int mt = 0; mt < 4; mt++) {
            #pragma unroll
            for (int r = 0; r < 4; r++) {
                int row = row0 + wm * 64 + mt * 16 + quad * 4 + r;
                C[(size_t)row * DM + col] = acc[mt][nt][r] + bv;
            }
        }
    }
}

// ---------------------------------------------------------------------------
// Flash attention, causal. Block = (q-tile of 64 rows, head). 4 waves, each
// owns 16 q rows. Keys iterated in tiles of 64. Q pre-scaled by 1/8 (exact
// in bf16). P round-trips through LDS (C-layout -> A-layout), V staged
// transposed so PV B-frags are contiguous ds_read_b128.
// ---------------------------------------------------------------------------
__global__ __launch_bounds__(256) void flash_attn(
    const bf16_t* __restrict__ Qb, const bf16_t* __restrict__ Kb,
    const bf16_t* __restrict__ Vb, bf16_t* __restrict__ Ctx)
{
    const int qi   = blockIdx.x;          // 0..63
    const int h    = blockIdx.y;          // 0..11
    const int tid  = threadIdx.x;
    const int wave = tid >> 6;
    const int lane = tid & 63;
    const int lrow = lane & 15;
    const int quad = lane >> 4;
    const int q0   = qi * 64;

    __shared__ bf16_t Ks[64][72];         // [key][dim], stride 144B -> 2-way
    __shared__ bf16_t Vt[64][72];         // [dim][key]
    __shared__ bf16_t Ps[4][16][72];      // per-wave P tile [q][key]

    // Q fragments for this wave's 16 rows: A-layout m=lrow, k=quad*8+j (+32s)
    const int qrow = q0 + wave * 16 + lrow;
    bf16x8 qfrag[2];
    #pragma unroll
    for (int s = 0; s < 2; s++) {
        bf16x8 t = *(const bf16x8*)&Qb[(size_t)qrow * DM + h * DK + s * 32 + quad * 8];
        #pragma unroll
        for (int j = 0; j < 8; j++)
            t[j] = (bf16_t)((float)t[j] * 0.125f);   // exact: power of two
        qfrag[s] = t;
    }

    f32x4 o[4];                            // O acc: row=quad*4+r, dim=nt*16+lrow
    #pragma unroll
    for (int nt = 0; nt < 4; nt++) o[nt] = (f32x4){0.f, 0.f, 0.f, 0.f};
    float m_i[4], l_i[4];
    #pragma unroll
    for (int r = 0; r < 4; r++) { m_i[r] = -1e30f; l_i[r] = 0.f; }

    for (int kt = 0; kt <= qi; kt++) {
        __syncthreads();                   // prev-iter LDS reads done
        // stage K [key][dim] and V^T [dim][key]
        #pragma unroll
        for (int i = 0; i < 2; i++) {
            int v   = tid + i * 256;       // 512 bf16x8 vectors, 8 per 64-dim row
            int key = v >> 3;              // FIX: was v>>2 (OOB LDS + unstaged dims)
            int c8  = v & 7;               // FIX: was v&3
            size_t g = (size_t)(kt * 64 + key) * DM + h * DK + c8 * 8;
            *(bf16x8*)&Ks[key][c8 * 8] = *(const bf16x8*)&Kb[g];
            bf16x8 vv = *(const bf16x8*)&Vb[g];
            #pragma unroll
            for (int j = 0; j < 8; j++) Vt[c8 * 8 + j][key] = vv[j];
        }
        __syncthreads();

        // S = Q K^T : scores row=q(quad*4+r), col=key(nt*16+lrow)
        f32x4 sc[4];
        #pragma unroll
        for (int nt = 0; nt < 4; nt++) {
            f32x4 a = (f32x4){0.f, 0.f, 0.f, 0.f};
            #pragma unroll
            for (int s = 0; s < 2; s++) {
                bf16x8 kb = *(const bf16x8*)&Ks[nt * 16 + lrow][s * 32 + quad * 8];
                a = __builtin_amdgcn_mfma_f32_16x16x32_bf16(qfrag[s], kb, a, 0, 0, 0);
            }
            sc[nt] = a;
        }

        if (kt == qi) {                    // causal mask within diagonal tile
            #pragma unroll
            for (int nt = 0; nt < 4; nt++)
                #pragma unroll
                for (int r = 0; r < 4; r++) {
                    int lq = wave * 16 + quad * 4 + r;
                    int lk = nt * 16 + lrow;
                    if (lk > lq) sc[nt][r] = -1e30f;
                }
        }

        // row max (over 4 ntiles locally, then across 16 lanes of the quad)
        float rmax[4];
        #pragma unroll
        for (int r = 0; r < 4; r++) {
            float v = sc[0][r];
            #pragma unroll
            for (int nt = 1; nt < 4; nt++) v = fmaxf(v, sc[nt][r]);
            rmax[r] = v;
        }
        #pragma unroll
        for (int off = 1; off < 16; off <<= 1)
            #pragma unroll
            for (int r = 0; r < 4; r++)
                rmax[r] = fmaxf(rmax[r], __shfl_xor(rmax[r], off, 64));

        float alpha[4];
        #pragma unroll
        for (int r = 0; r < 4; r++) {
            float mnew = fmaxf(m_i[r], rmax[r]);
            alpha[r] = __builtin_amdgcn_exp2f((m_i[r] - mnew) * LOG2E);
            m_i[r] = mnew;
        }

        float rsum[4] = {0.f, 0.f, 0.f, 0.f};
        #pragma unroll
        for (int nt = 0; nt < 4; nt++)
            #pragma unroll
            for (int r = 0; r < 4; r++) {
                float p = __builtin_amdgcn_exp2f((sc[nt][r] - m_i[r]) * LOG2E);
                sc[nt][r] = p;
                rsum[r] += p;
            }
        #pragma unroll
        for (int off = 1; off < 16; off <<= 1)
            #pragma unroll
            for (int r = 0; r < 4; r++)
                rsum[r] += __shfl_xor(rsum[r], off, 64);
        #pragma unroll
        for (int r = 0; r < 4; r++) l_i[r] = l_i[r] * alpha[r] + rsum[r];

        // P -> LDS (C-layout write)
        #pragma unroll
        for (int nt = 0; nt < 4; nt++)
            #pragma unroll
            for (int r = 0; r < 4; r++)
                Ps[wave][quad * 4 + r][nt * 16 + lrow] = (bf16_t)sc[nt][r];
        __syncthreads();                   // P write -> read ordering (safe)

        // rescale O, then O += P V
        #pragma unroll
        for (int nt = 0; nt < 4; nt++)
            #pragma unroll
            for (int r = 0; r < 4; r++)
                o[nt][r] *= alpha[r];
        #pragma unroll
        for (int s = 0; s < 2; s++) {
            bf16x8 pa = *(const bf16x8*)&Ps[wave][lrow][s * 32 + quad * 8];
            #pragma unroll
            for (int nt = 0; nt < 4; nt++) {
                bf16x8 vb = *(const bf16x8*)&Vt[nt * 16 + lrow][s * 32 + quad * 8];
                o[nt] = __builtin_amdgcn_mfma_f32_16x16x32_bf16(pa, vb, o[nt], 0, 0, 0);
            }
        }
    }

    // epilogue: /l, store ctx bf16
    #pragma unroll
    for (int nt = 0; nt < 4; nt++)
        #pragma unroll
        for (int r = 0; r < 4; r++) {
            int row = q0 + wave * 16 + quad * 4 + r;
            int col = h * DK + nt * 16 + lrow;
            Ctx[(size_t)row * DM + col] = (bf16_t)(o[nt][r] / l_i[r]);
        }
}

// ---------------------------------------------------------------------------
extern "C" void kernel_launch(void* const* d_in, const int* in_sizes, int n_in,
                              void* d_out, int out_size, void* d_ws, size_t ws_size,
                              hipStream_t stream) {
    const float* x  = (const float*)d_in[0];
    const float* Wq = (const float*)d_in[1];
    const float* bq = (const float*)d_in[2];
    const float* Wk = (const float*)d_in[3];
    const float* bk = (const float*)d_in[4];
    const float* Wv = (const float*)d_in[5];
    const float* bv = (const float*)d_in[6];
    const float* Wo = (const float*)d_in[7];
    const float* bo = (const float*)d_in[8];
    float* out = (float*)d_out;

    // workspace: Qb,Kb,Vb,Ctx bf16 [4096][768] each = 4 x 6.29 MB = 25.2 MB
    bf16_t* Qb = (bf16_t*)d_ws;
    bf16_t* Kb = Qb + (size_t)SEQ * DM;
    bf16_t* Vb = Kb + (size_t)SEQ * DM;
    bf16_t* Cx = Vb + (size_t)SEQ * DM;

    dim3 g1(SEQ / 128, DM / 128, 3);
    gemm_qkv<<<g1, 256, 0, stream>>>(x, Wq, bq, Wk, bk, Wv, bv, Qb, Kb, Vb);

    dim3 g2(SEQ / 64, NH);
    flash_attn<<<g2, 256, 0, stream>>>(Qb, Kb, Vb, Cx);

    dim3 g3(SEQ / 128, DM / 128);
    gemm_out<<<g3, 256, 0, stream>>>(Cx, Wo, bo, out);
}

// Round 3
// 294.779 us; speedup vs baseline: 1.3250x; 1.3250x over previous
//
#include <hip/hip_runtime.h>

#define SEQ 4096
#define DM  768
#define NH  12
#define DK  64

typedef __bf16 bf16_t;
typedef bf16_t bf16x8 __attribute__((ext_vector_type(8)));
typedef bf16_t bf16x4 __attribute__((ext_vector_type(4)));
typedef float  f32x4  __attribute__((ext_vector_type(4)));
typedef short  s16x4  __attribute__((ext_vector_type(4)));

#define LOG2E 1.44269504088896340736f

static __device__ inline f32x4 mfma16x16x16_bf16(bf16x4 a, bf16x4 b, f32x4 c) {
#if __has_builtin(__builtin_amdgcn_mfma_f32_16x16x16_bf16)
    return __builtin_amdgcn_mfma_f32_16x16x16_bf16(a, b, c, 0, 0, 0);
#else
    return __builtin_amdgcn_mfma_f32_16x16x16bf16_1k(
        __builtin_bit_cast(s16x4, a), __builtin_bit_cast(s16x4, b), c, 0, 0, 0);
#endif
}

// ---------------------------------------------------------------------------
// GEMM: C[M,N] = A[M,K] * W[N,K]^T + bias, A fp32, W fp32, C bf16.
// Fused over z = {Q,K,V}. Tile 128x128, BK=32, 4 waves each 64x64.
// z==2 (V) stores TRANSPOSED [DM][SEQ] so flash_attn stages V^T with
// conflict-free b128s (kills the 16-way-conflict LDS transpose).
// ---------------------------------------------------------------------------
__global__ __launch_bounds__(256) void gemm_qkv(
    const float* __restrict__ x,
    const float* __restrict__ Wq, const float* __restrict__ bq,
    const float* __restrict__ Wk, const float* __restrict__ bk,
    const float* __restrict__ Wv, const float* __restrict__ bv,
    bf16_t* __restrict__ Qb, bf16_t* __restrict__ Kb, bf16_t* __restrict__ Vbt)
{
    const float* W; const float* bias;
    if (blockIdx.z == 0)      { W = Wq; bias = bq; }
    else if (blockIdx.z == 1) { W = Wk; bias = bk; }
    else                      { W = Wv; bias = bv; }

    __shared__ bf16_t As[128][40];   // BK=32 + 8 pad -> 2-way (free)
    __shared__ bf16_t Bs[128][40];

    const int tid  = threadIdx.x;
    const int wave = tid >> 6;
    const int lane = tid & 63;
    const int wm   = wave & 1, wn = wave >> 1;
    const int lrow = lane & 15;
    const int quad = lane >> 4;
    const int row0 = blockIdx.x * 128;
    const int col0 = blockIdx.y * 128;

    f32x4 acc[4][4];
    #pragma unroll
    for (int i = 0; i < 4; i++)
        #pragma unroll
        for (int j = 0; j < 4; j++)
            acc[i][j] = (f32x4){0.f, 0.f, 0.f, 0.f};

    for (int k0 = 0; k0 < DM; k0 += 32) {
        __syncthreads();
        #pragma unroll
        for (int i = 0; i < 4; i++) {
            int v  = tid + i * 256;      // 1024 float4 vectors per matrix
            int r  = v >> 3;             // 8 float4 per 32-col row
            int c4 = v & 7;
            float4 av = *(const float4*)&x[(size_t)(row0 + r) * DM + k0 + c4 * 4];
            bf16x4 at;
            at[0] = (bf16_t)av.x; at[1] = (bf16_t)av.y;
            at[2] = (bf16_t)av.z; at[3] = (bf16_t)av.w;
            *(bf16x4*)&As[r][c4 * 4] = at;
            float4 bv4 = *(const float4*)&W[(size_t)(col0 + r) * DM + k0 + c4 * 4];
            bf16x4 bt;
            bt[0] = (bf16_t)bv4.x; bt[1] = (bf16_t)bv4.y;
            bt[2] = (bf16_t)bv4.z; bt[3] = (bf16_t)bv4.w;
            *(bf16x4*)&Bs[r][c4 * 4] = bt;
        }
        __syncthreads();

        bf16x8 afrag[4], bfrag[4];
        #pragma unroll
        for (int mt = 0; mt < 4; mt++)
            afrag[mt] = *(const bf16x8*)&As[wm * 64 + mt * 16 + lrow][quad * 8];
        #pragma unroll
        for (int nt = 0; nt < 4; nt++)
            bfrag[nt] = *(const bf16x8*)&Bs[wn * 64 + nt * 16 + lrow][quad * 8];
        #pragma unroll
        for (int mt = 0; mt < 4; mt++)
            #pragma unroll
            for (int nt = 0; nt < 4; nt++)
                acc[mt][nt] = __builtin_amdgcn_mfma_f32_16x16x32_bf16(
                    afrag[mt], bfrag[nt], acc[mt][nt], 0, 0, 0);
    }

    if (blockIdx.z == 2) {
        // V: store transposed [DM][SEQ], 4 consecutive rows per lane = bf16x4
        #pragma unroll
        for (int nt = 0; nt < 4; nt++) {
            int col = col0 + wn * 64 + nt * 16 + lrow;
            float bv = bias[col];
            #pragma unroll
            for (int mt = 0; mt < 4; mt++) {
                int row = row0 + wm * 64 + mt * 16 + quad * 4;
                bf16x4 t;
                #pragma unroll
                for (int r = 0; r < 4; r++) t[r] = (bf16_t)(acc[mt][nt][r] + bv);
                *(bf16x4*)&Vbt[(size_t)col * SEQ + row] = t;
            }
        }
    } else {
        bf16_t* Cout = (blockIdx.z == 0) ? Qb : Kb;
        #pragma unroll
        for (int nt = 0; nt < 4; nt++) {
            int col = col0 + wn * 64 + nt * 16 + lrow;
            float bv = bias[col];
            #pragma unroll
            for (int mt = 0; mt < 4; mt++) {
                #pragma unroll
                for (int r = 0; r < 4; r++) {
                    int row = row0 + wm * 64 + mt * 16 + quad * 4 + r;
                    Cout[(size_t)row * DM + col] = (bf16_t)(acc[mt][nt][r] + bv);
                }
            }
        }
    }
}

// ---------------------------------------------------------------------------
// GEMM: out[M,N] = A[M,K](bf16) * W[N,K]^T(fp32) + bias, out fp32.
// ---------------------------------------------------------------------------
__global__ __launch_bounds__(256) void gemm_out(
    const bf16_t* __restrict__ A, const float* __restrict__ W,
    const float* __restrict__ bias, float* __restrict__ C)
{
    __shared__ bf16_t As[128][40];
    __shared__ bf16_t Bs[128][40];

    const int tid  = threadIdx.x;
    const int wave = tid >> 6;
    const int lane = tid & 63;
    const int wm   = wave & 1, wn = wave >> 1;
    const int lrow = lane & 15;
    const int quad = lane >> 4;
    const int row0 = blockIdx.x * 128;
    const int col0 = blockIdx.y * 128;

    f32x4 acc[4][4];
    #pragma unroll
    for (int i = 0; i < 4; i++)
        #pragma unroll
        for (int j = 0; j < 4; j++)
            acc[i][j] = (f32x4){0.f, 0.f, 0.f, 0.f};

    for (int k0 = 0; k0 < DM; k0 += 32) {
        __syncthreads();
        #pragma unroll
        for (int i = 0; i < 2; i++) {       // A: 512 bf16x8 vectors
            int v  = tid + i * 256;
            int r  = v >> 2;                // 4 vectors per 32-col row
            int c8 = v & 3;
            *(bf16x8*)&As[r][c8 * 8] =
                *(const bf16x8*)&A[(size_t)(row0 + r) * DM + k0 + c8 * 8];
        }
        #pragma unroll
        for (int i = 0; i < 4; i++) {       // B: fp32 -> bf16
            int v  = tid + i * 256;
            int r  = v >> 3;
            int c4 = v & 7;
            float4 bv4 = *(const float4*)&W[(size_t)(col0 + r) * DM + k0 + c4 * 4];
            bf16x4 bt;
            bt[0] = (bf16_t)bv4.x; bt[1] = (bf16_t)bv4.y;
            bt[2] = (bf16_t)bv4.z; bt[3] = (bf16_t)bv4.w;
            *(bf16x4*)&Bs[r][c4 * 4] = bt;
        }
        __syncthreads();

        bf16x8 afrag[4], bfrag[4];
        #pragma unroll
        for (int mt = 0; mt < 4; mt++)
            afrag[mt] = *(const bf16x8*)&As[wm * 64 + mt * 16 + lrow][quad * 8];
        #pragma unroll
        for (int nt = 0; nt < 4; nt++)
            bfrag[nt] = *(const bf16x8*)&Bs[wn * 64 + nt * 16 + lrow][quad * 8];
        #pragma unroll
        for (int mt = 0; mt < 4; mt++)
            #pragma unroll
            for (int nt = 0; nt < 4; nt++)
                acc[mt][nt] = __builtin_amdgcn_mfma_f32_16x16x32_bf16(
                    afrag[mt], bfrag[nt], acc[mt][nt], 0, 0, 0);
    }

    #pragma unroll
    for (int nt = 0; nt < 4; nt++) {
        int col = col0 + wn * 64 + nt * 16 + lrow;
        float bv = bias[col];
        #pragma unroll
        for (int mt = 0; mt < 4; mt++) {
            #pragma unroll
            for (int r = 0; r < 4; r++) {
                int row = row0 + wm * 64 + mt * 16 + quad * 4 + r;
                C[(size_t)row * DM + col] = acc[mt][nt][r] + bv;
            }
        }
    }
}

// ---------------------------------------------------------------------------
// Flash attention, causal, transposed-score formulation.
// Block = (q-tile 64, head), 4 waves x 16 q. Keys in tiles of 64.
// S^T = K.Q^T  (C-layout: lane holds S[q=lrow][key=quad*4+r])
//   -> P is born in the B-fragment layout of mfma_16x16x16
// O^T = V^T.P^T (K=16 MFMAs) — no P LDS round-trip, no O-layout shuffle.
// V comes pre-transposed from gemm_qkv. 2 barriers/iter.
// ---------------------------------------------------------------------------
__global__ __launch_bounds__(256) void flash_attn(
    const bf16_t* __restrict__ Qb, const bf16_t* __restrict__ Kb,
    const bf16_t* __restrict__ Vbt, bf16_t* __restrict__ Ctx)
{
    const int qi   = gridDim.x - 1 - blockIdx.x;   // reversed: long blocks first
    const int h    = blockIdx.y;
    const int tid  = threadIdx.x;
    const int wave = tid >> 6;
    const int lane = tid & 63;
    const int lrow = lane & 15;
    const int quad = lane >> 4;
    const int q0   = qi * 64;

    __shared__ bf16_t Ks[64][72];   // [key][dim]  stride 144B -> 2-way (free)
    __shared__ bf16_t Vt[64][72];   // [dim][key]  staged straight from Vbt

    // Q B-fragments (n=lrow -> q, k=quad*8+j -> dim), scaled by 1/8 (exact)
    const int qrow = q0 + wave * 16 + lrow;
    bf16x8 qfrag[2];
    #pragma unroll
    for (int s = 0; s < 2; s++) {
        bf16x8 t = *(const bf16x8*)&Qb[(size_t)qrow * DM + h * DK + s * 32 + quad * 8];
        #pragma unroll
        for (int j = 0; j < 8; j++)
            t[j] = (bf16_t)((float)t[j] * 0.125f);
        qfrag[s] = t;
    }

    f32x4 oT[4];                    // O^T: row=d=dt*16+quad*4+r, col=q=lrow
    #pragma unroll
    for (int dt = 0; dt < 4; dt++) oT[dt] = (f32x4){0.f, 0.f, 0.f, 0.f};
    float m_i = -1e30f, l_i = 0.f;  // per-lane, q = lrow

    for (int kt = 0; kt <= qi; kt++) {
        __syncthreads();
        #pragma unroll
        for (int i = 0; i < 2; i++) {
            int v   = tid + i * 256;       // 512 slots: 64 rows x 8 vecs
            int row = v >> 3;
            int c8  = v & 7;
            *(bf16x8*)&Ks[row][c8 * 8] =
                *(const bf16x8*)&Kb[(size_t)(kt * 64 + row) * DM + h * DK + c8 * 8];
            *(bf16x8*)&Vt[row][c8 * 8] =
                *(const bf16x8*)&Vbt[(size_t)(h * DK + row) * SEQ + kt * 64 + c8 * 8];
        }
        __syncthreads();

        // S^T tiles: sc[mt][r] = S[q=lrow][key=16mt+quad*4+r]
        f32x4 sc[4];
        #pragma unroll
        for (int mt = 0; mt < 4; mt++) {
            f32x4 a = (f32x4){0.f, 0.f, 0.f, 0.f};
            #pragma unroll
            for (int s = 0; s < 2; s++) {
                bf16x8 kf = *(const bf16x8*)&Ks[mt * 16 + lrow][s * 32 + quad * 8];
                a = __builtin_amdgcn_mfma_f32_16x16x32_bf16(kf, qfrag[s], a, 0, 0, 0);
            }
            sc[mt] = a;
        }

        if (kt == qi) {                    // causal mask within diagonal tile
            int lq = wave * 16 + lrow;
            #pragma unroll
            for (int mt = 0; mt < 4; mt++)
                #pragma unroll
                for (int r = 0; r < 4; r++)
                    if (mt * 16 + quad * 4 + r > lq) sc[mt][r] = -1e30f;
        }

        // online softmax: q = lrow, reduce over quads (2 shuffle rounds)
        float rmax = -1e30f;
        #pragma unroll
        for (int mt = 0; mt < 4; mt++)
            #pragma unroll
            for (int r = 0; r < 4; r++) rmax = fmaxf(rmax, sc[mt][r]);
        rmax = fmaxf(rmax, __shfl_xor(rmax, 16, 64));
        rmax = fmaxf(rmax, __shfl_xor(rmax, 32, 64));

        float mnew  = fmaxf(m_i, rmax);
        float alpha = __builtin_amdgcn_exp2f((m_i - mnew) * LOG2E);
        m_i = mnew;

        float rsum = 0.f;
        #pragma unroll
        for (int mt = 0; mt < 4; mt++)
            #pragma unroll
            for (int r = 0; r < 4; r++) {
                float p = __builtin_amdgcn_exp2f((sc[mt][r] - mnew) * LOG2E);
                sc[mt][r] = p;
                rsum += p;
            }
        rsum += __shfl_xor(rsum, 16, 64);
        rsum += __shfl_xor(rsum, 32, 64);
        l_i = l_i * alpha + rsum;

        // P -> bf16 B-fragments (n=lrow=q, k=quad*4+j=key)
        bf16x4 pf[4];
        #pragma unroll
        for (int kb = 0; kb < 4; kb++) {
            bf16x4 t;
            #pragma unroll
            for (int j = 0; j < 4; j++) t[j] = (bf16_t)sc[kb][j];
            pf[kb] = t;
        }

        // O^T rescale + accumulate: A = V^T (m=lrow=d, k=quad*4+j=key)
        #pragma unroll
        for (int dt = 0; dt < 4; dt++) {
            #pragma unroll
            for (int r = 0; r < 4; r++) oT[dt][r] *= alpha;
            #pragma unroll
            for (int kb = 0; kb < 4; kb++) {
                bf16x4 vf = *(const bf16x4*)&Vt[dt * 16 + lrow][kb * 16 + quad * 4];
                oT[dt] = mfma16x16x16_bf16(vf, pf[kb], oT[dt]);
            }
        }
    }

    // epilogue: /l_i (per-lane), store O^T -> Ctx[q][h*64+d], bf16x4
    float inv_l = 1.f / l_i;
    #pragma unroll
    for (int dt = 0; dt < 4; dt++) {
        bf16x4 ov;
        #pragma unroll
        for (int r = 0; r < 4; r++) ov[r] = (bf16_t)(oT[dt][r] * inv_l);
        *(bf16x4*)&Ctx[(size_t)(q0 + wave * 16 + lrow) * DM
                       + h * DK + dt * 16 + quad * 4] = ov;
    }
}

// ---------------------------------------------------------------------------
extern "C" void kernel_launch(void* const* d_in, const int* in_sizes, int n_in,
                              void* d_out, int out_size, void* d_ws, size_t ws_size,
                              hipStream_t stream) {
    const float* x  = (const float*)d_in[0];
    const float* Wq = (const float*)d_in[1];
    const float* bq = (const float*)d_in[2];
    const float* Wk = (const float*)d_in[3];
    const float* bk = (const float*)d_in[4];
    const float* Wv = (const float*)d_in[5];
    const float* bv = (const float*)d_in[6];
    const float* Wo = (const float*)d_in[7];
    const float* bo = (const float*)d_in[8];
    float* out = (float*)d_out;

    bf16_t* Qb  = (bf16_t*)d_ws;
    bf16_t* Kb  = Qb  + (size_t)SEQ * DM;
    bf16_t* Vbt = Kb  + (size_t)SEQ * DM;   // transposed [DM][SEQ]
    bf16_t* Cx  = Vbt + (size_t)SEQ * DM;

    dim3 g1(SEQ / 128, DM / 128, 3);
    gemm_qkv<<<g1, 256, 0, stream>>>(x, Wq, bq, Wk, bk, Wv, bv, Qb, Kb, Vbt);

    dim3 g2(SEQ / 64, NH);
    flash_attn<<<g2, 256, 0, stream>>>(Qb, Kb, Vbt, Cx);

    dim3 g3(SEQ / 128, DM / 128);
    gemm_out<<<g3, 256, 0, stream>>>(Cx, Wo, bo, out);
}

// Round 4
// 232.331 us; speedup vs baseline: 1.6812x; 1.2688x over previous
//
#include <hip/hip_runtime.h>

#define SEQ 4096
#define DM  768
#define NH  12
#define DK  64

typedef __bf16 bf16_t;
typedef bf16_t bf16x8 __attribute__((ext_vector_type(8)));
typedef bf16_t bf16x4 __attribute__((ext_vector_type(4)));
typedef float  f32x4  __attribute__((ext_vector_type(4)));
typedef short  s16x4  __attribute__((ext_vector_type(4)));

#define LOG2E 1.44269504088896340736f
#define SM_C  16.0f   // fixed softmax shift: p = exp2((s - C)*log2e); scale cancels in O/l

static __device__ inline f32x4 mfma16x16x16_bf16(bf16x4 a, bf16x4 b, f32x4 c) {
#if __has_builtin(__builtin_amdgcn_mfma_f32_16x16x16_bf16)
    return __builtin_amdgcn_mfma_f32_16x16x16_bf16(a, b, c, 0, 0, 0);
#else
    return __builtin_amdgcn_mfma_f32_16x16x16bf16_1k(
        __builtin_bit_cast(s16x4, a), __builtin_bit_cast(s16x4, b), c, 0, 0, 0);
#endif
}

// ---------------------------------------------------------------------------
// GEMM: C[M,N] = A[M,K] * W[N,K]^T + bias, A fp32, W fp32, C bf16.
// Fused over z = {Q,K,V}. V stored transposed [DM][SEQ].
// ---------------------------------------------------------------------------
__global__ __launch_bounds__(256) void gemm_qkv(
    const float* __restrict__ x,
    const float* __restrict__ Wq, const float* __restrict__ bq,
    const float* __restrict__ Wk, const float* __restrict__ bk,
    const float* __restrict__ Wv, const float* __restrict__ bv,
    bf16_t* __restrict__ Qb, bf16_t* __restrict__ Kb, bf16_t* __restrict__ Vbt)
{
    const float* W; const float* bias;
    if (blockIdx.z == 0)      { W = Wq; bias = bq; }
    else if (blockIdx.z == 1) { W = Wk; bias = bk; }
    else                      { W = Wv; bias = bv; }

    __shared__ bf16_t As[128][40];
    __shared__ bf16_t Bs[128][40];

    const int tid  = threadIdx.x;
    const int wave = tid >> 6;
    const int lane = tid & 63;
    const int wm   = wave & 1, wn = wave >> 1;
    const int lrow = lane & 15;
    const int quad = lane >> 4;
    const int row0 = blockIdx.x * 128;
    const int col0 = blockIdx.y * 128;

    f32x4 acc[4][4];
    #pragma unroll
    for (int i = 0; i < 4; i++)
        #pragma unroll
        for (int j = 0; j < 4; j++)
            acc[i][j] = (f32x4){0.f, 0.f, 0.f, 0.f};

    for (int k0 = 0; k0 < DM; k0 += 32) {
        __syncthreads();
        #pragma unroll
        for (int i = 0; i < 4; i++) {
            int v  = tid + i * 256;
            int r  = v >> 3;
            int c4 = v & 7;
            float4 av = *(const float4*)&x[(size_t)(row0 + r) * DM + k0 + c4 * 4];
            bf16x4 at;
            at[0] = (bf16_t)av.x; at[1] = (bf16_t)av.y;
            at[2] = (bf16_t)av.z; at[3] = (bf16_t)av.w;
            *(bf16x4*)&As[r][c4 * 4] = at;
            float4 bv4 = *(const float4*)&W[(size_t)(col0 + r) * DM + k0 + c4 * 4];
            bf16x4 bt;
            bt[0] = (bf16_t)bv4.x; bt[1] = (bf16_t)bv4.y;
            bt[2] = (bf16_t)bv4.z; bt[3] = (bf16_t)bv4.w;
            *(bf16x4*)&Bs[r][c4 * 4] = bt;
        }
        __syncthreads();

        bf16x8 afrag[4], bfrag[4];
        #pragma unroll
        for (int mt = 0; mt < 4; mt++)
            afrag[mt] = *(const bf16x8*)&As[wm * 64 + mt * 16 + lrow][quad * 8];
        #pragma unroll
        for (int nt = 0; nt < 4; nt++)
            bfrag[nt] = *(const bf16x8*)&Bs[wn * 64 + nt * 16 + lrow][quad * 8];
        #pragma unroll
        for (int mt = 0; mt < 4; mt++)
            #pragma unroll
            for (int nt = 0; nt < 4; nt++)
                acc[mt][nt] = __builtin_amdgcn_mfma_f32_16x16x32_bf16(
                    afrag[mt], bfrag[nt], acc[mt][nt], 0, 0, 0);
    }

    if (blockIdx.z == 2) {
        #pragma unroll
        for (int nt = 0; nt < 4; nt++) {
            int col = col0 + wn * 64 + nt * 16 + lrow;
            float bv = bias[col];
            #pragma unroll
            for (int mt = 0; mt < 4; mt++) {
                int row = row0 + wm * 64 + mt * 16 + quad * 4;
                bf16x4 t;
                #pragma unroll
                for (int r = 0; r < 4; r++) t[r] = (bf16_t)(acc[mt][nt][r] + bv);
                *(bf16x4*)&Vbt[(size_t)col * SEQ + row] = t;
            }
        }
    } else {
        bf16_t* Cout = (blockIdx.z == 0) ? Qb : Kb;
        #pragma unroll
        for (int nt = 0; nt < 4; nt++) {
            int col = col0 + wn * 64 + nt * 16 + lrow;
            float bv = bias[col];
            #pragma unroll
            for (int mt = 0; mt < 4; mt++) {
                #pragma unroll
                for (int r = 0; r < 4; r++) {
                    int row = row0 + wm * 64 + mt * 16 + quad * 4 + r;
                    Cout[(size_t)row * DM + col] = (bf16_t)(acc[mt][nt][r] + bv);
                }
            }
        }
    }
}

// ---------------------------------------------------------------------------
// GEMM: out[M,N] = A[M,K](bf16) * W[N,K]^T(fp32) + bias, out fp32.
// ---------------------------------------------------------------------------
__global__ __launch_bounds__(256) void gemm_out(
    const bf16_t* __restrict__ A, const float* __restrict__ W,
    const float* __restrict__ bias, float* __restrict__ C)
{
    __shared__ bf16_t As[128][40];
    __shared__ bf16_t Bs[128][40];

    const int tid  = threadIdx.x;
    const int wave = tid >> 6;
    const int lane = tid & 63;
    const int wm   = wave & 1, wn = wave >> 1;
    const int lrow = lane & 15;
    const int quad = lane >> 4;
    const int row0 = blockIdx.x * 128;
    const int col0 = blockIdx.y * 128;

    f32x4 acc[4][4];
    #pragma unroll
    for (int i = 0; i < 4; i++)
        #pragma unroll
        for (int j = 0; j < 4; j++)
            acc[i][j] = (f32x4){0.f, 0.f, 0.f, 0.f};

    for (int k0 = 0; k0 < DM; k0 += 32) {
        __syncthreads();
        #pragma unroll
        for (int i = 0; i < 2; i++) {
            int v  = tid + i * 256;
            int r  = v >> 2;
            int c8 = v & 3;
            *(bf16x8*)&As[r][c8 * 8] =
                *(const bf16x8*)&A[(size_t)(row0 + r) * DM + k0 + c8 * 8];
        }
        #pragma unroll
        for (int i = 0; i < 4; i++) {
            int v  = tid + i * 256;
            int r  = v >> 3;
            int c4 = v & 7;
            float4 bv4 = *(const float4*)&W[(size_t)(col0 + r) * DM + k0 + c4 * 4];
            bf16x4 bt;
            bt[0] = (bf16_t)bv4.x; bt[1] = (bf16_t)bv4.y;
            bt[2] = (bf16_t)bv4.z; bt[3] = (bf16_t)bv4.w;
            *(bf16x4*)&Bs[r][c4 * 4] = bt;
        }
        __syncthreads();

        bf16x8 afrag[4], bfrag[4];
        #pragma unroll
        for (int mt = 0; mt < 4; mt++)
            afrag[mt] = *(const bf16x8*)&As[wm * 64 + mt * 16 + lrow][quad * 8];
        #pragma unroll
        for (int nt = 0; nt < 4; nt++)
            bfrag[nt] = *(const bf16x8*)&Bs[wn * 64 + nt * 16 + lrow][quad * 8];
        #pragma unroll
        for (int mt = 0; mt < 4; mt++)
            #pragma unroll
            for (int nt = 0; nt < 4; nt++)
                acc[mt][nt] = __builtin_amdgcn_mfma_f32_16x16x32_bf16(
                    afrag[mt], bfrag[nt], acc[mt][nt], 0, 0, 0);
    }

    #pragma unroll
    for (int nt = 0; nt < 4; nt++) {
        int col = col0 + wn * 64 + nt * 16 + lrow;
        float bv = bias[col];
        #pragma unroll
        for (int mt = 0; mt < 4; mt++) {
            #pragma unroll
            for (int r = 0; r < 4; r++) {
                int row = row0 + wm * 64 + mt * 16 + quad * 4 + r;
                C[(size_t)row * DM + col] = acc[mt][nt][r] + bv;
            }
        }
    }
}

// ---------------------------------------------------------------------------
// Flash attention, causal, transposed-score + fixed-shift softmax + register
// prefetch pipeline. Per iter: [B1] regs->LDS [B2] issue next loads, compute.
// No per-iter reductions: p = exp2((s-C)*log2e), l accumulated per-lane and
// reduced across quads once after the loop (scale cancels in O/l).
// ---------------------------------------------------------------------------
__global__ __launch_bounds__(256) void flash_attn(
    const bf16_t* __restrict__ Qb, const bf16_t* __restrict__ Kb,
    const bf16_t* __restrict__ Vbt, bf16_t* __restrict__ Ctx)
{
    const int qi   = gridDim.x - 1 - blockIdx.x;   // long blocks first
    const int h    = blockIdx.y;
    const int tid  = threadIdx.x;
    const int wave = tid >> 6;
    const int lane = tid & 63;
    const int lrow = lane & 15;
    const int quad = lane >> 4;
    const int q0   = qi * 64;

    __shared__ bf16_t Ks[64][72];   // stride 36 dwords: b128 reads conflict-free
    __shared__ bf16_t Vt[64][76];   // stride 38 dwords: b64 reads conflict-free

    // Q B-fragments (n=lrow -> q, k=quad*8+j -> dim), scaled by 1/8 (exact)
    const int qrow = q0 + wave * 16 + lrow;
    bf16x8 qfrag[2];
    #pragma unroll
    for (int s = 0; s < 2; s++) {
        bf16x8 t = *(const bf16x8*)&Qb[(size_t)qrow * DM + h * DK + s * 32 + quad * 8];
        #pragma unroll
        for (int j = 0; j < 8; j++)
            t[j] = (bf16_t)((float)t[j] * 0.125f);
        qfrag[s] = t;
    }

    f32x4 oT[4];                    // O^T: row=d=dt*16+quad*4+r, col=q=lrow
    #pragma unroll
    for (int dt = 0; dt < 4; dt++) oT[dt] = (f32x4){0.f, 0.f, 0.f, 0.f};
    float l_i = 0.f;                // per-lane partial (this quad's key blocks)

    // staging slots: each thread owns rows r0 and r0+32, 8 bf16 cols at c0
    const int r0 = tid >> 3;        // 0..31
    const int c0 = (tid & 7) * 8;   // 0,8,..,56

    const bf16_t* Kbase = Kb  + (size_t)h * DK + c0;
    const bf16_t* Vbase = Vbt + (size_t)(h * DK) * SEQ + c0;

    // prefetch tile 0
    bf16x8 kr0 = *(const bf16x8*)&Kbase[(size_t)(r0)      * DM];
    bf16x8 kr1 = *(const bf16x8*)&Kbase[(size_t)(r0 + 32) * DM];
    bf16x8 vr0 = *(const bf16x8*)&Vbase[(size_t)(r0)      * SEQ];
    bf16x8 vr1 = *(const bf16x8*)&Vbase[(size_t)(r0 + 32) * SEQ];

    for (int kt = 0; kt <= qi; kt++) {
        __syncthreads();                         // prior-iter LDS reads done
        *(bf16x8*)&Ks[r0][c0]      = kr0;        // vmcnt wait auto-inserted
        *(bf16x8*)&Ks[r0 + 32][c0] = kr1;
        *(bf16x8*)&Vt[r0][c0]      = vr0;
        *(bf16x8*)&Vt[r0 + 32][c0] = vr1;
        __syncthreads();                         // LDS visible

        if (kt < qi) {                           // issue next loads; latency
            size_t ko = (size_t)(kt + 1) * 64;   // hidden behind compute below
            kr0 = *(const bf16x8*)&Kbase[(ko + r0)      * DM];
            kr1 = *(const bf16x8*)&Kbase[(ko + r0 + 32) * DM];
            vr0 = *(const bf16x8*)&Vbase[(size_t)(r0)      * SEQ + ko];
            vr1 = *(const bf16x8*)&Vbase[(size_t)(r0 + 32) * SEQ + ko];
        }

        // S^T tiles: sc[mt][r] = S[q=lrow][key=16mt+quad*4+r]
        f32x4 sc[4];
        #pragma unroll
        for (int mt = 0; mt < 4; mt++) {
            f32x4 a = (f32x4){0.f, 0.f, 0.f, 0.f};
            #pragma unroll
            for (int s = 0; s < 2; s++) {
                bf16x8 kf = *(const bf16x8*)&Ks[mt * 16 + lrow][s * 32 + quad * 8];
                a = __builtin_amdgcn_mfma_f32_16x16x32_bf16(kf, qfrag[s], a, 0, 0, 0);
            }
            sc[mt] = a;
        }

        if (kt == qi) {                          // causal mask, diagonal tile
            int lq = wave * 16 + lrow;
            #pragma unroll
            for (int mt = 0; mt < 4; mt++)
                #pragma unroll
                for (int r = 0; r < 4; r++)
                    if (mt * 16 + quad * 4 + r > lq) sc[mt][r] = -1e30f;
        }

        // fixed-shift softmax: p = exp2((s - C)*log2e); no reductions here
        bf16x4 pf[4];
        float rsum = 0.f;
        #pragma unroll
        for (int mt = 0; mt < 4; mt++) {
            bf16x4 t;
            #pragma unroll
            for (int r = 0; r < 4; r++) {
                float p = __builtin_amdgcn_exp2f((sc[mt][r] - SM_C) * LOG2E);
                rsum += p;
                t[r] = (bf16_t)p;
            }
            pf[mt] = t;
        }
        l_i += rsum;

        // O^T += V^T P^T  (A: m=lrow=d, k=quad*4+j=key; B: n=lrow=q)
        #pragma unroll
        for (int dt = 0; dt < 4; dt++)
            #pragma unroll
            for (int kb = 0; kb < 4; kb++) {
                bf16x4 vf = *(const bf16x4*)&Vt[dt * 16 + lrow][kb * 16 + quad * 4];
                oT[dt] = mfma16x16x16_bf16(vf, pf[kb], oT[dt]);
            }
    }

    // single cross-quad reduction of l, then store
    l_i += __shfl_xor(l_i, 16, 64);
    l_i += __shfl_xor(l_i, 32, 64);
    float inv_l = 1.f / l_i;
    #pragma unroll
    for (int dt = 0; dt < 4; dt++) {
        bf16x4 ov;
        #pragma unroll
        for (int r = 0; r < 4; r++) ov[r] = (bf16_t)(oT[dt][r] * inv_l);
        *(bf16x4*)&Ctx[(size_t)(q0 + wave * 16 + lrow) * DM
                       + h * DK + dt * 16 + quad * 4] = ov;
    }
}

// ---------------------------------------------------------------------------
extern "C" void kernel_launch(void* const* d_in, const int* in_sizes, int n_in,
                              void* d_out, int out_size, void* d_ws, size_t ws_size,
                              hipStream_t stream) {
    const float* x  = (const float*)d_in[0];
    const float* Wq = (const float*)d_in[1];
    const float* bq = (const float*)d_in[2];
    const float* Wk = (const float*)d_in[3];
    const float* bk = (const float*)d_in[4];
    const float* Wv = (const float*)d_in[5];
    const float* bv = (const float*)d_in[6];
    const float* Wo = (const float*)d_in[7];
    const float* bo = (const float*)d_in[8];
    float* out = (float*)d_out;

    bf16_t* Qb  = (bf16_t*)d_ws;
    bf16_t* Kb  = Qb  + (size_t)SEQ * DM;
    bf16_t* Vbt = Kb  + (size_t)SEQ * DM;   // transposed [DM][SEQ]
    bf16_t* Cx  = Vbt + (size_t)SEQ * DM;

    dim3 g1(SEQ / 128, DM / 128, 3);
    gemm_qkv<<<g1, 256, 0, stream>>>(x, Wq, bq, Wk, bk, Wv, bv, Qb, Kb, Vbt);

    dim3 g2(SEQ / 64, NH);
    flash_attn<<<g2, 256, 0, stream>>>(Qb, Kb, Vbt, Cx);

    dim3 g3(SEQ / 128, DM / 128);
    gemm_out<<<g3, 256, 0, stream>>>(Cx, Wo, bo, out);
}

// Round 5
// 220.911 us; speedup vs baseline: 1.7681x; 1.0517x over previous
//
#include <hip/hip_runtime.h>

#define SEQ 4096
#define DM  768
#define NH  12
#define DK  64

typedef __bf16 bf16_t;
typedef bf16_t bf16x8 __attribute__((ext_vector_type(8)));
typedef bf16_t bf16x4 __attribute__((ext_vector_type(4)));
typedef float  f32x4  __attribute__((ext_vector_type(4)));
typedef short  s16x4  __attribute__((ext_vector_type(4)));

#define LOG2E 1.44269504088896340736f
#define SM_C  16.0f   // fixed softmax shift; scale cancels in O/l

static __device__ inline f32x4 mfma16x16x16_bf16(bf16x4 a, bf16x4 b, f32x4 c) {
#if __has_builtin(__builtin_amdgcn_mfma_f32_16x16x16_bf16)
    return __builtin_amdgcn_mfma_f32_16x16x16_bf16(a, b, c, 0, 0, 0);
#else
    return __builtin_amdgcn_mfma_f32_16x16x16bf16_1k(
        __builtin_bit_cast(s16x4, a), __builtin_bit_cast(s16x4, b), c, 0, 0, 0);
#endif
}

// ===========================================================================
// FANCY PATH (needs ~42.7 MB ws)
// ===========================================================================

// fp32 -> bf16 bulk convert: x (SEQ*DM) then Wq,Wk,Wv,Wo (DM*DM each)
__global__ __launch_bounds__(256) void cvt_bf16(
    const float* __restrict__ x,  const float* __restrict__ Wq,
    const float* __restrict__ Wk, const float* __restrict__ Wv,
    const float* __restrict__ Wo,
    bf16_t* __restrict__ xb, bf16_t* __restrict__ Wb /* 4x DM*DM */)
{
    const int NXV = SEQ * DM / 4;      // 786432
    const int NWV = DM * DM / 4;       // 147456
    int i4 = blockIdx.x * 256 + threadIdx.x;
    const float* src; bf16_t* dst; int off;
    if (i4 < NXV) { src = x; dst = xb; off = i4; }
    else {
        int j = i4 - NXV;
        int w = j / NWV, jj = j - w * NWV;
        src = (w == 0) ? Wq : (w == 1) ? Wk : (w == 2) ? Wv : Wo;
        dst = Wb + (size_t)w * DM * DM;
        off = jj;
    }
    float4 v = *(const float4*)&src[(size_t)off * 4];
    bf16x4 t;
    t[0] = (bf16_t)v.x; t[1] = (bf16_t)v.y; t[2] = (bf16_t)v.z; t[3] = (bf16_t)v.w;
    *(bf16x4*)&dst[(size_t)off * 4] = t;
}

// GEMM: C[M,N] = A[M,K](bf16) * W[N,K]^T(bf16) + bias(f32), C bf16.
// z selects {Q,K,V}; V stored transposed [DM][SEQ].
__global__ __launch_bounds__(256) void gemm_qkv_b(
    const bf16_t* __restrict__ A, const bf16_t* __restrict__ Wb,
    const float* __restrict__ bq, const float* __restrict__ bk,
    const float* __restrict__ bv,
    bf16_t* __restrict__ Qb, bf16_t* __restrict__ Kb, bf16_t* __restrict__ Vbt)
{
    const int z = blockIdx.z;
    const bf16_t* W = Wb + (size_t)z * DM * DM;
    const float* bias = (z == 0) ? bq : (z == 1) ? bk : bv;

    __shared__ bf16_t As[128][40];
    __shared__ bf16_t Bs[128][40];

    const int tid  = threadIdx.x;
    const int wave = tid >> 6;
    const int lane = tid & 63;
    const int wm   = wave & 1, wn = wave >> 1;
    const int lrow = lane & 15;
    const int quad = lane >> 4;
    const int row0 = blockIdx.x * 128;
    const int col0 = blockIdx.y * 128;

    f32x4 acc[4][4];
    #pragma unroll
    for (int i = 0; i < 4; i++)
        #pragma unroll
        for (int j = 0; j < 4; j++)
            acc[i][j] = (f32x4){0.f, 0.f, 0.f, 0.f};

    for (int k0 = 0; k0 < DM; k0 += 32) {
        __syncthreads();
        #pragma unroll
        for (int i = 0; i < 2; i++) {
            int v  = tid + i * 256;
            int r  = v >> 2;
            int c8 = v & 3;
            *(bf16x8*)&As[r][c8 * 8] =
                *(const bf16x8*)&A[(size_t)(row0 + r) * DM + k0 + c8 * 8];
            *(bf16x8*)&Bs[r][c8 * 8] =
                *(const bf16x8*)&W[(size_t)(col0 + r) * DM + k0 + c8 * 8];
        }
        __syncthreads();

        bf16x8 afrag[4], bfrag[4];
        #pragma unroll
        for (int mt = 0; mt < 4; mt++)
            afrag[mt] = *(const bf16x8*)&As[wm * 64 + mt * 16 + lrow][quad * 8];
        #pragma unroll
        for (int nt = 0; nt < 4; nt++)
            bfrag[nt] = *(const bf16x8*)&Bs[wn * 64 + nt * 16 + lrow][quad * 8];
        #pragma unroll
        for (int mt = 0; mt < 4; mt++)
            #pragma unroll
            for (int nt = 0; nt < 4; nt++)
                acc[mt][nt] = __builtin_amdgcn_mfma_f32_16x16x32_bf16(
                    afrag[mt], bfrag[nt], acc[mt][nt], 0, 0, 0);
    }

    if (z == 2) {
        #pragma unroll
        for (int nt = 0; nt < 4; nt++) {
            int col = col0 + wn * 64 + nt * 16 + lrow;
            float bvv = bias[col];
            #pragma unroll
            for (int mt = 0; mt < 4; mt++) {
                int row = row0 + wm * 64 + mt * 16 + quad * 4;
                bf16x4 t;
                #pragma unroll
                for (int r = 0; r < 4; r++) t[r] = (bf16_t)(acc[mt][nt][r] + bvv);
                *(bf16x4*)&Vbt[(size_t)col * SEQ + row] = t;
            }
        }
    } else {
        bf16_t* Cout = (z == 0) ? Qb : Kb;
        #pragma unroll
        for (int nt = 0; nt < 4; nt++) {
            int col = col0 + wn * 64 + nt * 16 + lrow;
            float bvv = bias[col];
            #pragma unroll
            for (int mt = 0; mt < 4; mt++) {
                #pragma unroll
                for (int r = 0; r < 4; r++) {
                    int row = row0 + wm * 64 + mt * 16 + quad * 4 + r;
                    Cout[(size_t)row * DM + col] = (bf16_t)(acc[mt][nt][r] + bvv);
                }
            }
        }
    }
}

// GEMM: out[M,N](f32) = A[M,K](bf16) * W[N,K]^T(bf16) + bias(f32)
__global__ __launch_bounds__(256) void gemm_out_b(
    const bf16_t* __restrict__ A, const bf16_t* __restrict__ W,
    const float* __restrict__ bias, float* __restrict__ C)
{
    __shared__ bf16_t As[128][40];
    __shared__ bf16_t Bs[128][40];

    const int tid  = threadIdx.x;
    const int wave = tid >> 6;
    const int lane = tid & 63;
    const int wm   = wave & 1, wn = wave >> 1;
    const int lrow = lane & 15;
    const int quad = lane >> 4;
    const int row0 = blockIdx.x * 128;
    const int col0 = blockIdx.y * 128;

    f32x4 acc[4][4];
    #pragma unroll
    for (int i = 0; i < 4; i++)
        #pragma unroll
        for (int j = 0; j < 4; j++)
            acc[i][j] = (f32x4){0.f, 0.f, 0.f, 0.f};

    for (int k0 = 0; k0 < DM; k0 += 32) {
        __syncthreads();
        #pragma unroll
        for (int i = 0; i < 2; i++) {
            int v  = tid + i * 256;
            int r  = v >> 2;
            int c8 = v & 3;
            *(bf16x8*)&As[r][c8 * 8] =
                *(const bf16x8*)&A[(size_t)(row0 + r) * DM + k0 + c8 * 8];
            *(bf16x8*)&Bs[r][c8 * 8] =
                *(const bf16x8*)&W[(size_t)(col0 + r) * DM + k0 + c8 * 8];
        }
        __syncthreads();

        bf16x8 afrag[4], bfrag[4];
        #pragma unroll
        for (int mt = 0; mt < 4; mt++)
            afrag[mt] = *(const bf16x8*)&As[wm * 64 + mt * 16 + lrow][quad * 8];
        #pragma unroll
        for (int nt = 0; nt < 4; nt++)
            bfrag[nt] = *(const bf16x8*)&Bs[wn * 64 + nt * 16 + lrow][quad * 8];
        #pragma unroll
        for (int mt = 0; mt < 4; mt++)
            #pragma unroll
            for (int nt = 0; nt < 4; nt++)
                acc[mt][nt] = __builtin_amdgcn_mfma_f32_16x16x32_bf16(
                    afrag[mt], bfrag[nt], acc[mt][nt], 0, 0, 0);
    }

    #pragma unroll
    for (int nt = 0; nt < 4; nt++) {
        int col = col0 + wn * 64 + nt * 16 + lrow;
        float bvv = bias[col];
        #pragma unroll
        for (int mt = 0; mt < 4; mt++) {
            #pragma unroll
            for (int r = 0; r < 4; r++) {
                int row = row0 + wm * 64 + mt * 16 + quad * 4 + r;
                C[(size_t)row * DM + col] = acc[mt][nt][r] + bvv;
            }
        }
    }
}

// Flash attention, key-split. Fixed-shift softmax makes partials over
// disjoint key ranges additive: O = sum p*v, l = sum p -> fp32 atomics.
// grid (qi 64, chunk 8, h 12); chunk covers key tiles [8c, 8c+7] & <= qi.
__global__ __launch_bounds__(256) void flash_split(
    const bf16_t* __restrict__ Qb, const bf16_t* __restrict__ Kb,
    const bf16_t* __restrict__ Vbt,
    float* __restrict__ Oacc /* [NH][DK][SEQ] */,
    float* __restrict__ Lacc /* [NH][SEQ] */)
{
    const int qi = blockIdx.x;
    const int s0 = blockIdx.y * 8;
    if (s0 > qi) return;                         // block-uniform exit
    const int h    = blockIdx.z;
    const int kend = min(s0 + 7, qi);
    const int tid  = threadIdx.x;
    const int wave = tid >> 6;
    const int lane = tid & 63;
    const int lrow = lane & 15;
    const int quad = lane >> 4;
    const int q0   = qi * 64;

    __shared__ bf16_t Ks[64][72];
    __shared__ bf16_t Vt[64][76];

    const int qrow = q0 + wave * 16 + lrow;
    bf16x8 qfrag[2];
    #pragma unroll
    for (int s = 0; s < 2; s++) {
        bf16x8 t = *(const bf16x8*)&Qb[(size_t)qrow * DM + h * DK + s * 32 + quad * 8];
        #pragma unroll
        for (int j = 0; j < 8; j++)
            t[j] = (bf16_t)((float)t[j] * 0.125f);
        qfrag[s] = t;
    }

    f32x4 oT[4];
    #pragma unroll
    for (int dt = 0; dt < 4; dt++) oT[dt] = (f32x4){0.f, 0.f, 0.f, 0.f};
    float l_i = 0.f;

    const int r0 = tid >> 3;
    const int c0 = (tid & 7) * 8;
    const bf16_t* Kbase = Kb  + (size_t)h * DK + c0;
    const bf16_t* Vbase = Vbt + (size_t)(h * DK) * SEQ + c0;

    size_t ko = (size_t)s0 * 64;
    bf16x8 kr0 = *(const bf16x8*)&Kbase[(ko + r0)      * DM];
    bf16x8 kr1 = *(const bf16x8*)&Kbase[(ko + r0 + 32) * DM];
    bf16x8 vr0 = *(const bf16x8*)&Vbase[(size_t)(r0)      * SEQ + ko];
    bf16x8 vr1 = *(const bf16x8*)&Vbase[(size_t)(r0 + 32) * SEQ + ko];

    for (int kt = s0; kt <= kend; kt++) {
        __syncthreads();
        *(bf16x8*)&Ks[r0][c0]      = kr0;
        *(bf16x8*)&Ks[r0 + 32][c0] = kr1;
        *(bf16x8*)&Vt[r0][c0]      = vr0;
        *(bf16x8*)&Vt[r0 + 32][c0] = vr1;
        __syncthreads();

        if (kt < kend) {
            size_t kn = (size_t)(kt + 1) * 64;
            kr0 = *(const bf16x8*)&Kbase[(kn + r0)      * DM];
            kr1 = *(const bf16x8*)&Kbase[(kn + r0 + 32) * DM];
            vr0 = *(const bf16x8*)&Vbase[(size_t)(r0)      * SEQ + kn];
            vr1 = *(const bf16x8*)&Vbase[(size_t)(r0 + 32) * SEQ + kn];
        }

        f32x4 sc[4];
        #pragma unroll
        for (int mt = 0; mt < 4; mt++) {
            f32x4 a = (f32x4){0.f, 0.f, 0.f, 0.f};
            #pragma unroll
            for (int s = 0; s < 2; s++) {
                bf16x8 kf = *(const bf16x8*)&Ks[mt * 16 + lrow][s * 32 + quad * 8];
                a = __builtin_amdgcn_mfma_f32_16x16x32_bf16(kf, qfrag[s], a, 0, 0, 0);
            }
            sc[mt] = a;
        }

        if (kt == qi) {
            int lq = wave * 16 + lrow;
            #pragma unroll
            for (int mt = 0; mt < 4; mt++)
                #pragma unroll
                for (int r = 0; r < 4; r++)
                    if (mt * 16 + quad * 4 + r > lq) sc[mt][r] = -1e30f;
        }

        bf16x4 pf[4];
        float rsum = 0.f;
        #pragma unroll
        for (int mt = 0; mt < 4; mt++) {
            bf16x4 t;
            #pragma unroll
            for (int r = 0; r < 4; r++) {
                float p = __builtin_amdgcn_exp2f((sc[mt][r] - SM_C) * LOG2E);
                rsum += p;
                t[r] = (bf16_t)p;
            }
            pf[mt] = t;
        }
        l_i += rsum;

        #pragma unroll
        for (int dt = 0; dt < 4; dt++)
            #pragma unroll
            for (int kb = 0; kb < 4; kb++) {
                bf16x4 vf = *(const bf16x4*)&Vt[dt * 16 + lrow][kb * 16 + quad * 4];
                oT[dt] = mfma16x16x16_bf16(vf, pf[kb], oT[dt]);
            }
    }

    // accumulate partials: O^T into Oacc[h][d][q] (q-contiguous), l once/quad0
    #pragma unroll
    for (int dt = 0; dt < 4; dt++)
        #pragma unroll
        for (int r = 0; r < 4; r++) {
            int d = dt * 16 + quad * 4 + r;
            atomicAdd(&Oacc[((size_t)h * DK + d) * SEQ + q0 + wave * 16 + lrow],
                      oT[dt][r]);
        }
    l_i += __shfl_xor(l_i, 16, 64);
    l_i += __shfl_xor(l_i, 32, 64);
    if (quad == 0)
        atomicAdd(&Lacc[(size_t)h * SEQ + qrow], l_i);
}

// Ctx[q][h*64+d] = Oacc[h][d][q] / Lacc[h][q]  (LDS transpose, bf16 out)
__global__ __launch_bounds__(256) void ctx_epilogue(
    const float* __restrict__ Oacc, const float* __restrict__ Lacc,
    bf16_t* __restrict__ Ctx)
{
    const int qt = blockIdx.x;      // 64 q-tiles
    const int h  = blockIdx.y;
    const int tid = threadIdx.x;
    __shared__ float T[64][65];

    #pragma unroll
    for (int i = 0; i < 4; i++) {
        int v  = tid + i * 256;     // 0..1023
        int d  = v >> 4;
        int qv = v & 15;
        f32x4 o4 = *(const f32x4*)&Oacc[((size_t)h * DK + d) * SEQ + qt * 64 + qv * 4];
        f32x4 l4 = *(const f32x4*)&Lacc[(size_t)h * SEQ + qt * 64 + qv * 4];
        #pragma unroll
        for (int j = 0; j < 4; j++)
            T[qv * 4 + j][d] = o4[j] / l4[j];
    }
    __syncthreads();
    #pragma unroll
    for (int i = 0; i < 2; i++) {
        int v  = tid + i * 256;     // 0..511
        int q  = v >> 3;
        int c8 = v & 7;
        bf16x8 t;
        #pragma unroll
        for (int j = 0; j < 8; j++)
            t[j] = (bf16_t)T[q][c8 * 8 + j];
        *(bf16x8*)&Ctx[(size_t)(qt * 64 + q) * DM + h * DK + c8 * 8] = t;
    }
}

// ===========================================================================
// FALLBACK PATH (round-4, needs 25.2 MB ws)
// ===========================================================================
__global__ __launch_bounds__(256) void gemm_qkv_f32(
    const float* __restrict__ x,
    const float* __restrict__ Wq, const float* __restrict__ bq,
    const float* __restrict__ Wk, const float* __restrict__ bk,
    const float* __restrict__ Wv, const float* __restrict__ bv,
    bf16_t* __restrict__ Qb, bf16_t* __restrict__ Kb, bf16_t* __restrict__ Vbt)
{
    const float* W; const float* bias;
    if (blockIdx.z == 0)      { W = Wq; bias = bq; }
    else if (blockIdx.z == 1) { W = Wk; bias = bk; }
    else                      { W = Wv; bias = bv; }

    __shared__ bf16_t As[128][40];
    __shared__ bf16_t Bs[128][40];

    const int tid  = threadIdx.x;
    const int wave = tid >> 6;
    const int lane = tid & 63;
    const int wm   = wave & 1, wn = wave >> 1;
    const int lrow = lane & 15;
    const int quad = lane >> 4;
    const int row0 = blockIdx.x * 128;
    const int col0 = blockIdx.y * 128;

    f32x4 acc[4][4];
    #pragma unroll
    for (int i = 0; i < 4; i++)
        #pragma unroll
        for (int j = 0; j < 4; j++)
            acc[i][j] = (f32x4){0.f, 0.f, 0.f, 0.f};

    for (int k0 = 0; k0 < DM; k0 += 32) {
        __syncthreads();
        #pragma unroll
        for (int i = 0; i < 4; i++) {
            int v  = tid + i * 256;
            int r  = v >> 3;
            int c4 = v & 7;
            float4 av = *(const float4*)&x[(size_t)(row0 + r) * DM + k0 + c4 * 4];
            bf16x4 at;
            at[0] = (bf16_t)av.x; at[1] = (bf16_t)av.y;
            at[2] = (bf16_t)av.z; at[3] = (bf16_t)av.w;
            *(bf16x4*)&As[r][c4 * 4] = at;
            float4 bv4 = *(const float4*)&W[(size_t)(col0 + r) * DM + k0 + c4 * 4];
            bf16x4 bt;
            bt[0] = (bf16_t)bv4.x; bt[1] = (bf16_t)bv4.y;
            bt[2] = (bf16_t)bv4.z; bt[3] = (bf16_t)bv4.w;
            *(bf16x4*)&Bs[r][c4 * 4] = bt;
        }
        __syncthreads();

        bf16x8 afrag[4], bfrag[4];
        #pragma unroll
        for (int mt = 0; mt < 4; mt++)
            afrag[mt] = *(const bf16x8*)&As[wm * 64 + mt * 16 + lrow][quad * 8];
        #pragma unroll
        for (int nt = 0; nt < 4; nt++)
            bfrag[nt] = *(const bf16x8*)&Bs[wn * 64 + nt * 16 + lrow][quad * 8];
        #pragma unroll
        for (int mt = 0; mt < 4; mt++)
            #pragma unroll
            for (int nt = 0; nt < 4; nt++)
                acc[mt][nt] = __builtin_amdgcn_mfma_f32_16x16x32_bf16(
                    afrag[mt], bfrag[nt], acc[mt][nt], 0, 0, 0);
    }

    if (blockIdx.z == 2) {
        #pragma unroll
        for (int nt = 0; nt < 4; nt++) {
            int col = col0 + wn * 64 + nt * 16 + lrow;
            float bvv = bias[col];
            #pragma unroll
            for (int mt = 0; mt < 4; mt++) {
                int row = row0 + wm * 64 + mt * 16 + quad * 4;
                bf16x4 t;
                #pragma unroll
                for (int r = 0; r < 4; r++) t[r] = (bf16_t)(acc[mt][nt][r] + bvv);
                *(bf16x4*)&Vbt[(size_t)col * SEQ + row] = t;
            }
        }
    } else {
        bf16_t* Cout = (blockIdx.z == 0) ? Qb : Kb;
        #pragma unroll
        for (int nt = 0; nt < 4; nt++) {
            int col = col0 + wn * 64 + nt * 16 + lrow;
            float bvv = bias[col];
            #pragma unroll
            for (int mt = 0; mt < 4; mt++) {
                #pragma unroll
                for (int r = 0; r < 4; r++) {
                    int row = row0 + wm * 64 + mt * 16 + quad * 4 + r;
                    Cout[(size_t)row * DM + col] = (bf16_t)(acc[mt][nt][r] + bvv);
                }
            }
        }
    }
}

__global__ __launch_bounds__(256) void gemm_out_f32(
    const bf16_t* __restrict__ A, const float* __restrict__ W,
    const float* __restrict__ bias, float* __restrict__ C)
{
    __shared__ bf16_t As[128][40];
    __shared__ bf16_t Bs[128][40];

    const int tid  = threadIdx.x;
    const int wave = tid >> 6;
    const int lane = tid & 63;
    const int wm   = wave & 1, wn = wave >> 1;
    const int lrow = lane & 15;
    const int quad = lane >> 4;
    const int row0 = blockIdx.x * 128;
    const int col0 = blockIdx.y * 128;

    f32x4 acc[4][4];
    #pragma unroll
    for (int i = 0; i < 4; i++)
        #pragma unroll
        for (int j = 0; j < 4; j++)
            acc[i][j] = (f32x4){0.f, 0.f, 0.f, 0.f};

    for (int k0 = 0; k0 < DM; k0 += 32) {
        __syncthreads();
        #pragma unroll
        for (int i = 0; i < 2; i++) {
            int v  = tid + i * 256;
            int r  = v >> 2;
            int c8 = v & 3;
            *(bf16x8*)&As[r][c8 * 8] =
                *(const bf16x8*)&A[(size_t)(row0 + r) * DM + k0 + c8 * 8];
        }
        #pragma unroll
        for (int i = 0; i < 4; i++) {
            int v  = tid + i * 256;
            int r  = v >> 3;
            int c4 = v & 7;
            float4 bv4 = *(const float4*)&W[(size_t)(col0 + r) * DM + k0 + c4 * 4];
            bf16x4 bt;
            bt[0] = (bf16_t)bv4.x; bt[1] = (bf16_t)bv4.y;
            bt[2] = (bf16_t)bv4.z; bt[3] = (bf16_t)bv4.w;
            *(bf16x4*)&Bs[r][c4 * 4] = bt;
        }
        __syncthreads();

        bf16x8 afrag[4], bfrag[4];
        #pragma unroll
        for (int mt = 0; mt < 4; mt++)
            afrag[mt] = *(const bf16x8*)&As[wm * 64 + mt * 16 + lrow][quad * 8];
        #pragma unroll
        for (int nt = 0; nt < 4; nt++)
            bfrag[nt] = *(const bf16x8*)&Bs[wn * 64 + nt * 16 + lrow][quad * 8];
        #pragma unroll
        for (int mt = 0; mt < 4; mt++)
            #pragma unroll
            for (int nt = 0; nt < 4; nt++)
                acc[mt][nt] = __builtin_amdgcn_mfma_f32_16x16x32_bf16(
                    afrag[mt], bfrag[nt], acc[mt][nt], 0, 0, 0);
    }

    #pragma unroll
    for (int nt = 0; nt < 4; nt++) {
        int col = col0 + wn * 64 + nt * 16 + lrow;
        float bvv = bias[col];
        #pragma unroll
        for (int mt = 0; mt < 4; mt++) {
            #pragma unroll
            for (int r = 0; r < 4; r++) {
                int row = row0 + wm * 64 + mt * 16 + quad * 4 + r;
                C[(size_t)row * DM + col] = acc[mt][nt][r] + bvv;
            }
        }
    }
}

__global__ __launch_bounds__(256) void flash_attn_r4(
    const bf16_t* __restrict__ Qb, const bf16_t* __restrict__ Kb,
    const bf16_t* __restrict__ Vbt, bf16_t* __restrict__ Ctx)
{
    const int qi   = gridDim.x - 1 - blockIdx.x;
    const int h    = blockIdx.y;
    const int tid  = threadIdx.x;
    const int wave = tid >> 6;
    const int lane = tid & 63;
    const int lrow = lane & 15;
    const int quad = lane >> 4;
    const int q0   = qi * 64;

    __shared__ bf16_t Ks[64][72];
    __shared__ bf16_t Vt[64][76];

    const int qrow = q0 + wave * 16 + lrow;
    bf16x8 qfrag[2];
    #pragma unroll
    for (int s = 0; s < 2; s++) {
        bf16x8 t = *(const bf16x8*)&Qb[(size_t)qrow * DM + h * DK + s * 32 + quad * 8];
        #pragma unroll
        for (int j = 0; j < 8; j++)
            t[j] = (bf16_t)((float)t[j] * 0.125f);
        qfrag[s] = t;
    }

    f32x4 oT[4];
    #pragma unroll
    for (int dt = 0; dt < 4; dt++) oT[dt] = (f32x4){0.f, 0.f, 0.f, 0.f};
    float l_i = 0.f;

    const int r0 = tid >> 3;
    const int c0 = (tid & 7) * 8;
    const bf16_t* Kbase = Kb  + (size_t)h * DK + c0;
    const bf16_t* Vbase = Vbt + (size_t)(h * DK) * SEQ + c0;

    bf16x8 kr0 = *(const bf16x8*)&Kbase[(size_t)(r0)      * DM];
    bf16x8 kr1 = *(const bf16x8*)&Kbase[(size_t)(r0 + 32) * DM];
    bf16x8 vr0 = *(const bf16x8*)&Vbase[(size_t)(r0)      * SEQ];
    bf16x8 vr1 = *(const bf16x8*)&Vbase[(size_t)(r0 + 32) * SEQ];

    for (int kt = 0; kt <= qi; kt++) {
        __syncthreads();
        *(bf16x8*)&Ks[r0][c0]      = kr0;
        *(bf16x8*)&Ks[r0 + 32][c0] = kr1;
        *(bf16x8*)&Vt[r0][c0]      = vr0;
        *(bf16x8*)&Vt[r0 + 32][c0] = vr1;
        __syncthreads();

        if (kt < qi) {
            size_t ko = (size_t)(kt + 1) * 64;
            kr0 = *(const bf16x8*)&Kbase[(ko + r0)      * DM];
            kr1 = *(const bf16x8*)&Kbase[(ko + r0 + 32) * DM];
            vr0 = *(const bf16x8*)&Vbase[(size_t)(r0)      * SEQ + ko];
            vr1 = *(const bf16x8*)&Vbase[(size_t)(r0 + 32) * SEQ + ko];
        }

        f32x4 sc[4];
        #pragma unroll
        for (int mt = 0; mt < 4; mt++) {
            f32x4 a = (f32x4){0.f, 0.f, 0.f, 0.f};
            #pragma unroll
            for (int s = 0; s < 2; s++) {
                bf16x8 kf = *(const bf16x8*)&Ks[mt * 16 + lrow][s * 32 + quad * 8];
                a = __builtin_amdgcn_mfma_f32_16x16x32_bf16(kf, qfrag[s], a, 0, 0, 0);
            }
            sc[mt] = a;
        }

        if (kt == qi) {
            int lq = wave * 16 + lrow;
            #pragma unroll
            for (int mt = 0; mt < 4; mt++)
                #pragma unroll
                for (int r = 0; r < 4; r++)
                    if (mt * 16 + quad * 4 + r > lq) sc[mt][r] = -1e30f;
        }

        bf16x4 pf[4];
        float rsum = 0.f;
        #pragma unroll
        for (int mt = 0; mt < 4; mt++) {
            bf16x4 t;
            #pragma unroll
            for (int r = 0; r < 4; r++) {
                float p = __builtin_amdgcn_exp2f((sc[mt][r] - SM_C) * LOG2E);
                rsum += p;
                t[r] = (bf16_t)p;
            }
            pf[mt] = t;
        }
        l_i += rsum;

        #pragma unroll
        for (int dt = 0; dt < 4; dt++)
            #pragma unroll
            for (int kb = 0; kb < 4; kb++) {
                bf16x4 vf = *(const bf16x4*)&Vt[dt * 16 + lrow][kb * 16 + quad * 4];
                oT[dt] = mfma16x16x16_bf16(vf, pf[kb], oT[dt]);
            }
    }

    l_i += __shfl_xor(l_i, 16, 64);
    l_i += __shfl_xor(l_i, 32, 64);
    float inv_l = 1.f / l_i;
    #pragma unroll
    for (int dt = 0; dt < 4; dt++) {
        bf16x4 ov;
        #pragma unroll
        for (int r = 0; r < 4; r++) ov[r] = (bf16_t)(oT[dt][r] * inv_l);
        *(bf16x4*)&Ctx[(size_t)(q0 + wave * 16 + lrow) * DM
                       + h * DK + dt * 16 + quad * 4] = ov;
    }
}

// ---------------------------------------------------------------------------
extern "C" void kernel_launch(void* const* d_in, const int* in_sizes, int n_in,
                              void* d_out, int out_size, void* d_ws, size_t ws_size,
                              hipStream_t stream) {
    const float* x  = (const float*)d_in[0];
    const float* Wq = (const float*)d_in[1];
    const float* bq = (const float*)d_in[2];
    const float* Wk = (const float*)d_in[3];
    const float* bk = (const float*)d_in[4];
    const float* Wv = (const float*)d_in[5];
    const float* bv = (const float*)d_in[6];
    const float* Wo = (const float*)d_in[7];
    const float* bo = (const float*)d_in[8];
    float* out = (float*)d_out;

    const size_t NX = (size_t)SEQ * DM;        // 3145728
    const size_t NW = (size_t)DM * DM;         // 589824
    // fancy layout: xb | Qb | Kb | Vbt (bf16) | Wb x4 (bf16) | Oacc | Lacc (f32)
    const size_t need = (4 * NX + 4 * NW) * 2 + (NX + (size_t)NH * SEQ) * 4;

    if (ws_size >= need) {
        bf16_t* xb   = (bf16_t*)d_ws;          // reused as Ctx after flash
        bf16_t* Qb   = xb  + NX;
        bf16_t* Kb   = Qb  + NX;
        bf16_t* Vbt  = Kb  + NX;
        bf16_t* Wb   = Vbt + NX;               // Wq,Wk,Wv,Wo bf16
        float*  Oacc = (float*)(Wb + 4 * NW);
        float*  Lacc = Oacc + NX;              // NH*DK*SEQ == NX
        bf16_t* Cx   = xb;

        int cvt_blocks = (int)((NX + 4 * NW) / 4 / 256);   // 5376
        cvt_bf16<<<cvt_blocks, 256, 0, stream>>>(x, Wq, Wk, Wv, Wo, xb, Wb);
        hipMemsetAsync(Oacc, 0, (NX + (size_t)NH * SEQ) * 4, stream);

        dim3 g1(SEQ / 128, DM / 128, 3);
        gemm_qkv_b<<<g1, 256, 0, stream>>>(xb, Wb, bq, bk, bv, Qb, Kb, Vbt);

        dim3 g2(SEQ / 64, 8, NH);
        flash_split<<<g2, 256, 0, stream>>>(Qb, Kb, Vbt, Oacc, Lacc);

        dim3 g3(SEQ / 64, NH);
        ctx_epilogue<<<g3, 256, 0, stream>>>(Oacc, Lacc, Cx);

        dim3 g4(SEQ / 128, DM / 128);
        gemm_out_b<<<g4, 256, 0, stream>>>(Cx, Wb + 3 * NW, bo, out);
    } else {
        // round-4 fallback (25.2 MB)
        bf16_t* Qb  = (bf16_t*)d_ws;
        bf16_t* Kb  = Qb  + NX;
        bf16_t* Vbt = Kb  + NX;
        bf16_t* Cx  = Vbt + NX;

        dim3 g1(SEQ / 128, DM / 128, 3);
        gemm_qkv_f32<<<g1, 256, 0, stream>>>(x, Wq, bq, Wk, bk, Wv, bv, Qb, Kb, Vbt);
        dim3 g2(SEQ / 64, NH);
        flash_attn_r4<<<g2, 256, 0, stream>>>(Qb, Kb, Vbt, Cx);
        dim3 g3(SEQ / 128, DM / 128);
        gemm_out_f32<<<g3, 256, 0, stream>>>(Cx, Wo, bo, out);
    }
}

// Round 6
// 200.920 us; speedup vs baseline: 1.9440x; 1.0995x over previous
//
#include <hip/hip_runtime.h>

#define SEQ 4096
#define DM  768
#define NH  12
#define DK  64

typedef __bf16 bf16_t;
typedef bf16_t bf16x8 __attribute__((ext_vector_type(8)));
typedef bf16_t bf16x4 __attribute__((ext_vector_type(4)));
typedef float  f32x4  __attribute__((ext_vector_type(4)));
typedef short  s16x4  __attribute__((ext_vector_type(4)));

#define LOG2E 1.44269504088896340736f
#define SM_C  16.0f   // fixed softmax shift; scale cancels in O/l

static __device__ inline f32x4 mfma16x16x16_bf16(bf16x4 a, bf16x4 b, f32x4 c) {
#if __has_builtin(__builtin_amdgcn_mfma_f32_16x16x16_bf16)
    return __builtin_amdgcn_mfma_f32_16x16x16_bf16(a, b, c, 0, 0, 0);
#else
    return __builtin_amdgcn_mfma_f32_16x16x16bf16_1k(
        __builtin_bit_cast(s16x4, a), __builtin_bit_cast(s16x4, b), c, 0, 0, 0);
#endif
}

// async global->LDS, 16 B per lane; LDS dest = wave-uniform base + lane*16
static __device__ __forceinline__ void gl_lds16(const bf16_t* g, bf16_t* l) {
    __builtin_amdgcn_global_load_lds(
        (const __attribute__((address_space(1))) void*)g,
        (__attribute__((address_space(3))) void*)l, 16, 0, 0);
}

// ---------------------------------------------------------------------------
// fp32 -> bf16 bulk convert: x (SEQ*DM) then Wq,Wk,Wv,Wo (DM*DM each)
// ---------------------------------------------------------------------------
__global__ __launch_bounds__(256) void cvt_bf16(
    const float* __restrict__ x,  const float* __restrict__ Wq,
    const float* __restrict__ Wk, const float* __restrict__ Wv,
    const float* __restrict__ Wo,
    bf16_t* __restrict__ xb, bf16_t* __restrict__ Wb)
{
    const int NXV = SEQ * DM / 4;
    const int NWV = DM * DM / 4;
    int i4 = blockIdx.x * 256 + threadIdx.x;
    const float* src; bf16_t* dst; int off;
    if (i4 < NXV) { src = x; dst = xb; off = i4; }
    else {
        int j = i4 - NXV;
        int w = j / NWV, jj = j - w * NWV;
        src = (w == 0) ? Wq : (w == 1) ? Wk : (w == 2) ? Wv : Wo;
        dst = Wb + (size_t)w * DM * DM;
        off = jj;
    }
    float4 v = *(const float4*)&src[(size_t)off * 4];
    bf16x4 t;
    t[0] = (bf16_t)v.x; t[1] = (bf16_t)v.y; t[2] = (bf16_t)v.z; t[3] = (bf16_t)v.w;
    *(bf16x4*)&dst[(size_t)off * 4] = t;
}

// ---------------------------------------------------------------------------
// m97-style GEMM (BK=64, global_load_lds 16B, XOR-chunk swizzle).
// C[M,N] = A[M,K](bf16)*W[N,K]^T(bf16)+bias. z = {Q,K,V}; K pre-scaled by
// 1/8; V stored transposed [DM][SEQ].
// Swizzle: chunk j (16B) of row R stored at position j^(R&7); b128 frag
// reads then touch every bank exactly 8x (wave64 minimum).
// ---------------------------------------------------------------------------
__global__ __launch_bounds__(256) void gemm_qkv2(
    const bf16_t* __restrict__ A, const bf16_t* __restrict__ Wb,
    const float* __restrict__ bq, const float* __restrict__ bk,
    const float* __restrict__ bv,
    bf16_t* __restrict__ Qb, bf16_t* __restrict__ Kb, bf16_t* __restrict__ Vbt)
{
    const int z = blockIdx.z;
    const bf16_t* W = Wb + (size_t)z * DM * DM;
    const float* bias = (z == 0) ? bq : (z == 1) ? bk : bv;

    __shared__ bf16_t As[128][64];   // unpadded (global_load_lds) + swizzle
    __shared__ bf16_t Bs[128][64];

    const int tid  = threadIdx.x;
    const int wave = tid >> 6;
    const int lane = tid & 63;
    const int wm   = wave & 1, wn = wave >> 1;
    const int lrow = lane & 15;
    const int quad = lane >> 4;
    const int row0 = blockIdx.x * 128;
    const int col0 = blockIdx.y * 128;

    const int srow   = lane >> 3;            // 0..7 within 8-row load group
    const int schunk = (lane & 7) ^ srow;    // swizzled source chunk
    const int swz    = lrow & 7;             // frag-read swizzle key

    f32x4 acc[4][4];
    #pragma unroll
    for (int i = 0; i < 4; i++)
        #pragma unroll
        for (int j = 0; j < 4; j++)
            acc[i][j] = (f32x4){0.f, 0.f, 0.f, 0.f};

    for (int k0 = 0; k0 < DM; k0 += 64) {
        __syncthreads();
        #pragma unroll
        for (int u = 0; u < 4; u++) {
            int R0 = wave * 32 + u * 8;
            gl_lds16(&A[(size_t)(row0 + R0 + srow) * DM + k0 + schunk * 8],
                     &As[R0][0]);
            gl_lds16(&W[(size_t)(col0 + R0 + srow) * DM + k0 + schunk * 8],
                     &Bs[R0][0]);
        }
        __syncthreads();   // compiler drains vmcnt here

        #pragma unroll
        for (int s = 0; s < 2; s++) {
            bf16x8 af[4], bfr[4];
            #pragma unroll
            for (int mt = 0; mt < 4; mt++)
                af[mt] = *(const bf16x8*)
                    &As[wm * 64 + mt * 16 + lrow][(((s << 2) | quad) ^ swz) * 8];
            #pragma unroll
            for (int nt = 0; nt < 4; nt++)
                bfr[nt] = *(const bf16x8*)
                    &Bs[wn * 64 + nt * 16 + lrow][(((s << 2) | quad) ^ swz) * 8];
            #pragma unroll
            for (int mt = 0; mt < 4; mt++)
                #pragma unroll
                for (int nt = 0; nt < 4; nt++)
                    acc[mt][nt] = __builtin_amdgcn_mfma_f32_16x16x32_bf16(
                        af[mt], bfr[nt], acc[mt][nt], 0, 0, 0);
        }
    }

    if (z == 2) {          // V transposed [DM][SEQ]
        #pragma unroll
        for (int nt = 0; nt < 4; nt++) {
            int col = col0 + wn * 64 + nt * 16 + lrow;
            float bvv = bias[col];
            #pragma unroll
            for (int mt = 0; mt < 4; mt++) {
                int row = row0 + wm * 64 + mt * 16 + quad * 4;
                bf16x4 t;
                #pragma unroll
                for (int r = 0; r < 4; r++) t[r] = (bf16_t)(acc[mt][nt][r] + bvv);
                *(bf16x4*)&Vbt[(size_t)col * SEQ + row] = t;
            }
        }
    } else {
        bf16_t* Cout = (z == 0) ? Qb : Kb;
        float scale = (z == 1) ? 0.125f : 1.0f;   // fold 1/sqrt(dk) into K
        #pragma unroll
        for (int nt = 0; nt < 4; nt++) {
            int col = col0 + wn * 64 + nt * 16 + lrow;
            float bvv = bias[col];
            #pragma unroll
            for (int mt = 0; mt < 4; mt++) {
                #pragma unroll
                for (int r = 0; r < 4; r++) {
                    int row = row0 + wm * 64 + mt * 16 + quad * 4 + r;
                    Cout[(size_t)row * DM + col] =
                        (bf16_t)((acc[mt][nt][r] + bvv) * scale);
                }
            }
        }
    }
}

// ---------------------------------------------------------------------------
// out[M,N](f32) = A[M,K](bf16)*W[N,K]^T(bf16)+bias. Tile 128x64 (384 blocks).
// ---------------------------------------------------------------------------
__global__ __launch_bounds__(256) void gemm_out2(
    const bf16_t* __restrict__ A, const bf16_t* __restrict__ W,
    const float* __restrict__ bias, float* __restrict__ C)
{
    __shared__ bf16_t As[128][64];
    __shared__ bf16_t Bs[64][64];

    const int tid  = threadIdx.x;
    const int wave = tid >> 6;
    const int lane = tid & 63;
    const int wm   = wave & 1, wn = wave >> 1;   // wm: 64-row half, wn: 32-col half
    const int lrow = lane & 15;
    const int quad = lane >> 4;
    const int row0 = blockIdx.x * 128;
    const int col0 = blockIdx.y * 64;

    const int srow   = lane >> 3;
    const int schunk = (lane & 7) ^ srow;
    const int swz    = lrow & 7;

    f32x4 acc[4][2];
    #pragma unroll
    for (int i = 0; i < 4; i++)
        #pragma unroll
        for (int j = 0; j < 2; j++)
            acc[i][j] = (f32x4){0.f, 0.f, 0.f, 0.f};

    for (int k0 = 0; k0 < DM; k0 += 64) {
        __syncthreads();
        #pragma unroll
        for (int u = 0; u < 4; u++) {
            int R0 = wave * 32 + u * 8;
            gl_lds16(&A[(size_t)(row0 + R0 + srow) * DM + k0 + schunk * 8],
                     &As[R0][0]);
        }
        #pragma unroll
        for (int u = 0; u < 2; u++) {
            int R0 = wave * 16 + u * 8;
            gl_lds16(&W[(size_t)(col0 + R0 + srow) * DM + k0 + schunk * 8],
                     &Bs[R0][0]);
        }
        __syncthreads();

        #pragma unroll
        for (int s = 0; s < 2; s++) {
            bf16x8 af[4], bfr[2];
            #pragma unroll
            for (int mt = 0; mt < 4; mt++)
                af[mt] = *(const bf16x8*)
                    &As[wm * 64 + mt * 16 + lrow][(((s << 2) | quad) ^ swz) * 8];
            #pragma unroll
            for (int nt = 0; nt < 2; nt++)
                bfr[nt] = *(const bf16x8*)
                    &Bs[wn * 32 + nt * 16 + lrow][(((s << 2) | quad) ^ swz) * 8];
            #pragma unroll
            for (int mt = 0; mt < 4; mt++)
                #pragma unroll
                for (int nt = 0; nt < 2; nt++)
                    acc[mt][nt] = __builtin_amdgcn_mfma_f32_16x16x32_bf16(
                        af[mt], bfr[nt], acc[mt][nt], 0, 0, 0);
        }
    }

    #pragma unroll
    for (int nt = 0; nt < 2; nt++) {
        int col = col0 + wn * 32 + nt * 16 + lrow;
        float bvv = bias[col];
        #pragma unroll
        for (int mt = 0; mt < 4; mt++) {
            #pragma unroll
            for (int r = 0; r < 4; r++) {
                int row = row0 + wm * 64 + mt * 16 + quad * 4 + r;
                C[(size_t)row * DM + col] = acc[mt][nt][r] + bvv;
            }
        }
    }
}

// ---------------------------------------------------------------------------
// Flash attention, key-split (chunk=16 tiles), LDS double-buffer (1 barrier
// per iter), transposed scores, fixed-shift softmax. K pre-scaled by 1/8.
// Partials additive -> fp32 atomics into Oacc/Lacc.
// ---------------------------------------------------------------------------
__global__ __launch_bounds__(256) void flash_split2(
    const bf16_t* __restrict__ Qb, const bf16_t* __restrict__ Kb,
    const bf16_t* __restrict__ Vbt,
    float* __restrict__ Oacc /* [NH][DK][SEQ] */,
    float* __restrict__ Lacc /* [NH][SEQ] */)
{
    const int qi = blockIdx.x;
    const int s0 = blockIdx.y * 16;
    if (s0 > qi) return;
    const int h    = blockIdx.z;
    const int kend = min(s0 + 15, qi);
    const int tid  = threadIdx.x;
    const int wave = tid >> 6;
    const int lane = tid & 63;
    const int lrow = lane & 15;
    const int quad = lane >> 4;
    const int q0   = qi * 64;

    __shared__ bf16_t Ks[2][64][72];
    __shared__ bf16_t Vt[2][64][76];

    const int qrow = q0 + wave * 16 + lrow;
    bf16x8 qfrag[2];
    #pragma unroll
    for (int s = 0; s < 2; s++)
        qfrag[s] = *(const bf16x8*)&Qb[(size_t)qrow * DM + h * DK + s * 32 + quad * 8];

    f32x4 oT[4];
    #pragma unroll
    for (int dt = 0; dt < 4; dt++) oT[dt] = (f32x4){0.f, 0.f, 0.f, 0.f};
    float l_i = 0.f;

    const int r0 = tid >> 3;
    const int c0 = (tid & 7) * 8;
    const bf16_t* Kbase = Kb  + (size_t)h * DK + c0;
    const bf16_t* Vbase = Vbt + (size_t)(h * DK) * SEQ + c0;

    size_t ko = (size_t)s0 * 64;
    bf16x8 kr0 = *(const bf16x8*)&Kbase[(ko + r0)      * DM];
    bf16x8 kr1 = *(const bf16x8*)&Kbase[(ko + r0 + 32) * DM];
    bf16x8 vr0 = *(const bf16x8*)&Vbase[(size_t)(r0)      * SEQ + ko];
    bf16x8 vr1 = *(const bf16x8*)&Vbase[(size_t)(r0 + 32) * SEQ + ko];

    for (int kt = s0; kt <= kend; kt++) {
        const int b = kt & 1;
        // write prefetched tile into buffer b (other waves may still be
        // reading buffer b^1 of iter kt-1 -- disjoint, safe)
        *(bf16x8*)&Ks[b][r0][c0]      = kr0;
        *(bf16x8*)&Ks[b][r0 + 32][c0] = kr1;
        *(bf16x8*)&Vt[b][r0][c0]      = vr0;
        *(bf16x8*)&Vt[b][r0 + 32][c0] = vr1;
        __syncthreads();               // single barrier per iteration

        if (kt < kend) {               // prefetch next tile (latency hidden)
            size_t kn = (size_t)(kt + 1) * 64;
            kr0 = *(const bf16x8*)&Kbase[(kn + r0)      * DM];
            kr1 = *(const bf16x8*)&Kbase[(kn + r0 + 32) * DM];
            vr0 = *(const bf16x8*)&Vbase[(size_t)(r0)      * SEQ + kn];
            vr1 = *(const bf16x8*)&Vbase[(size_t)(r0 + 32) * SEQ + kn];
        }

        f32x4 sc[4];
        #pragma unroll
        for (int mt = 0; mt < 4; mt++) {
            f32x4 a = (f32x4){0.f, 0.f, 0.f, 0.f};
            #pragma unroll
            for (int s = 0; s < 2; s++) {
                bf16x8 kf = *(const bf16x8*)&Ks[b][mt * 16 + lrow][s * 32 + quad * 8];
                a = __builtin_amdgcn_mfma_f32_16x16x32_bf16(kf, qfrag[s], a, 0, 0, 0);
            }
            sc[mt] = a;
        }

        if (kt == qi) {                // causal mask, diagonal tile
            int lq = wave * 16 + lrow;
            #pragma unroll
            for (int mt = 0; mt < 4; mt++)
                #pragma unroll
                for (int r = 0; r < 4; r++)
                    if (mt * 16 + quad * 4 + r > lq) sc[mt][r] = -1e30f;
        }

        bf16x4 pf[4];
        float rsum = 0.f;
        #pragma unroll
        for (int mt = 0; mt < 4; mt++) {
            bf16x4 t;
            #pragma unroll
            for (int r = 0; r < 4; r++) {
                float p = __builtin_amdgcn_exp2f((sc[mt][r] - SM_C) * LOG2E);
                rsum += p;
                t[r] = (bf16_t)p;
            }
            pf[mt] = t;
        }
        l_i += rsum;

        #pragma unroll
        for (int dt = 0; dt < 4; dt++)
            #pragma unroll
            for (int kb = 0; kb < 4; kb++) {
                bf16x4 vf = *(const bf16x4*)&Vt[b][dt * 16 + lrow][kb * 16 + quad * 4];
                oT[dt] = mfma16x16x16_bf16(vf, pf[kb], oT[dt]);
            }
    }

    #pragma unroll
    for (int dt = 0; dt < 4; dt++)
        #pragma unroll
        for (int r = 0; r < 4; r++) {
            int d = dt * 16 + quad * 4 + r;
            atomicAdd(&Oacc[((size_t)h * DK + d) * SEQ + q0 + wave * 16 + lrow],
                      oT[dt][r]);
        }
    l_i += __shfl_xor(l_i, 16, 64);
    l_i += __shfl_xor(l_i, 32, 64);
    if (quad == 0)
        atomicAdd(&Lacc[(size_t)h * SEQ + qrow], l_i);
}

// ---------------------------------------------------------------------------
// Ctx[q][h*64+d] = Oacc[h][d][q] / Lacc[h][q]
// ---------------------------------------------------------------------------
__global__ __launch_bounds__(256) void ctx_epilogue(
    const float* __restrict__ Oacc, const float* __restrict__ Lacc,
    bf16_t* __restrict__ Ctx)
{
    const int qt = blockIdx.x;
    const int h  = blockIdx.y;
    const int tid = threadIdx.x;
    __shared__ float T[64][65];

    #pragma unroll
    for (int i = 0; i < 4; i++) {
        int v  = tid + i * 256;
        int d  = v >> 4;
        int qv = v & 15;
        f32x4 o4 = *(const f32x4*)&Oacc[((size_t)h * DK + d) * SEQ + qt * 64 + qv * 4];
        f32x4 l4 = *(const f32x4*)&Lacc[(size_t)h * SEQ + qt * 64 + qv * 4];
        #pragma unroll
        for (int j = 0; j < 4; j++)
            T[qv * 4 + j][d] = o4[j] / l4[j];
    }
    __syncthreads();
    #pragma unroll
    for (int i = 0; i < 2; i++) {
        int v  = tid + i * 256;
        int q  = v >> 3;
        int c8 = v & 7;
        bf16x8 t;
        #pragma unroll
        for (int j = 0; j < 8; j++)
            t[j] = (bf16_t)T[q][c8 * 8 + j];
        *(bf16x8*)&Ctx[(size_t)(qt * 64 + q) * DM + h * DK + c8 * 8] = t;
    }
}

// ---------------------------------------------------------------------------
extern "C" void kernel_launch(void* const* d_in, const int* in_sizes, int n_in,
                              void* d_out, int out_size, void* d_ws, size_t ws_size,
                              hipStream_t stream) {
    const float* x  = (const float*)d_in[0];
    const float* Wq = (const float*)d_in[1];
    const float* bq = (const float*)d_in[2];
    const float* Wk = (const float*)d_in[3];
    const float* bk = (const float*)d_in[4];
    const float* Wv = (const float*)d_in[5];
    const float* bv = (const float*)d_in[6];
    const float* Wo = (const float*)d_in[7];
    const float* bo = (const float*)d_in[8];
    float* out = (float*)d_out;

    const size_t NX = (size_t)SEQ * DM;
    const size_t NW = (size_t)DM * DM;

    bf16_t* xb   = (bf16_t*)d_ws;          // reused as Ctx after flash
    bf16_t* Qb   = xb  + NX;
    bf16_t* Kb   = Qb  + NX;
    bf16_t* Vbt  = Kb  + NX;               // transposed [DM][SEQ]
    bf16_t* Wb   = Vbt + NX;               // Wq,Wk,Wv,Wo bf16
    float*  Oacc = (float*)(Wb + 4 * NW);
    float*  Lacc = Oacc + NX;
    bf16_t* Cx   = xb;

    int cvt_blocks = (int)((NX + 4 * NW) / 4 / 256);
    cvt_bf16<<<cvt_blocks, 256, 0, stream>>>(x, Wq, Wk, Wv, Wo, xb, Wb);
    hipMemsetAsync(Oacc, 0, (NX + (size_t)NH * SEQ) * 4, stream);

    dim3 g1(SEQ / 128, DM / 128, 3);
    gemm_qkv2<<<g1, 256, 0, stream>>>(xb, Wb, bq, bk, bv, Qb, Kb, Vbt);

    dim3 g2(SEQ / 64, 4, NH);
    flash_split2<<<g2, 256, 0, stream>>>(Qb, Kb, Vbt, Oacc, Lacc);

    dim3 g3(SEQ / 64, NH);
    ctx_epilogue<<<g3, 256, 0, stream>>>(Oacc, Lacc, Cx);

    dim3 g4(SEQ / 128, DM / 64);
    gemm_out2<<<g4, 256, 0, stream>>>(Cx, Wb + 3 * NW, bo, out);
}